// Round 1
// 611.092 us; speedup vs baseline: 1.0289x; 1.0289x over previous
//
#include <hip/hip_runtime.h>
#include <stdint.h>

// Problem constants
#define BD   16
#define CD   512
#define HD_  64
#define NH_  8
#define HWD  4096
#define LD   77
#define DD   768

typedef __bf16 bf16;
typedef bf16 bf16x8 __attribute__((ext_vector_type(8)));
typedef float f32x4 __attribute__((ext_vector_type(4)));

__device__ __forceinline__ void async16(const bf16* g, bf16* l) {
  __builtin_amdgcn_global_load_lds(
      (const __attribute__((address_space(1))) void*)g,
      (__attribute__((address_space(3))) void*)l, 16, 0, 0);
}

__device__ __forceinline__ unsigned short bfb(float f) {
  bf16 h = (bf16)f;
  return __builtin_bit_cast(unsigned short, h);
}

// ---------------------------------------------------------------------------
// K0a: transpose+convert x [B,C,HW] f32 -> xt [B*HW, C] bf16 (LDS tile xpose)
// ---------------------------------------------------------------------------
__global__ __launch_bounds__(256) void xpose_cvt(const float* __restrict__ X,
                                                 bf16* __restrict__ Y) {
  __shared__ float tile[64][68];
  const int b = blockIdx.z, c0 = blockIdx.y * 64, t0 = blockIdx.x * 64;
  const int tid = threadIdx.x;
  const float* Xb = X + ((size_t)b * CD + c0) * HWD + t0;
#pragma unroll
  for (int p = 0; p < 4; ++p) {
    int c = (tid >> 4) + p * 16;
    int t = (tid & 15) * 4;
    float4 v = *(const float4*)(Xb + (size_t)c * HWD + t);
    *(float4*)&tile[c][t] = v;
  }
  __syncthreads();
  int t = tid >> 2, cb = (tid & 3) * 16;
  union { uint4 u[2]; unsigned short us[16]; } pk;
#pragma unroll
  for (int j = 0; j < 16; ++j) pk.us[j] = bfb(tile[cb + j][t]);
  uint4* Yp = (uint4*)(Y + ((size_t)(b * HWD + t0 + t)) * CD + c0 + cb);
  Yp[0] = pk.u[0];
  Yp[1] = pk.u[1];
}

// ---------------------------------------------------------------------------
// K0b: generic f32 -> bf16 convert (n multiple of 8)
// ---------------------------------------------------------------------------
__global__ void cvt_bf16_k(const float* __restrict__ X, bf16* __restrict__ Y, int n) {
  int i = (blockIdx.x * 256 + threadIdx.x) * 8;
  if (i >= n) return;
  float4 a = *(const float4*)(X + i);
  float4 c = *(const float4*)(X + i + 4);
  union { uint4 u; unsigned short us[8]; } pk;
  pk.us[0] = bfb(a.x); pk.us[1] = bfb(a.y); pk.us[2] = bfb(a.z); pk.us[3] = bfb(a.w);
  pk.us[4] = bfb(c.x); pk.us[5] = bfb(c.y); pk.us[6] = bfb(c.z); pk.us[7] = bfb(c.w);
  *(uint4*)(Y + i) = pk.u;
}

// ---------------------------------------------------------------------------
// m97-style GEMM: D[M,N] = A[M,K] * B[N,K]^T (+ mode-specific epilogue)
// MODE 1: K/V-proj-> D fp32 [M,512], += bias[n], rows guarded by M
// MODE 3: O-proj  -> m = out-channel, n = token; D = out[B,C,HW] fp32,
//                    += bo[m] + x[b,m,hw] residual
// ---------------------------------------------------------------------------
template <int TM, int TN, int MODE>
__global__ __launch_bounds__(256)
void gemm_bt(const bf16* __restrict__ A, const bf16* __restrict__ B,
             int M, int N, int K,
             const float* __restrict__ bias, const float* __restrict__ xres,
             float* __restrict__ D) {
  constexpr int WM = TM / 2, WN = TN / 2;
  constexpr int AFR = WM / 16, BFR = WN / 16;
  constexpr int ACH = TM / 8, TCH = (TM + TN) / 8, WCH = TCH / 4;
  __shared__ bf16 sA[TM * 64];
  __shared__ bf16 sB[TN * 64];
  const int tid = threadIdx.x, wave = tid >> 6, lane = tid & 63;
  const int m0 = blockIdx.y * TM, n0 = blockIdx.x * TN;
  const int wm = (wave >> 1) * WM, wn = (wave & 1) * WN;
  const int sub = lane >> 3, col8 = (lane & 7) * 8;
  const int mlo = lane & 15, khi = lane >> 4;
  f32x4 acc[AFR][BFR] = {};

  for (int k0 = 0; k0 < K; k0 += 64) {
#pragma unroll
    for (int r = 0; r < WCH; ++r) {
      int ci = wave * WCH + r;
      if (ci < ACH) {
        int row = ci * 8 + sub;
        int g = m0 + row;
        if (g > M - 1) g = M - 1;  // clamp partial M-tiles (KV GEMM)
        async16(A + (size_t)g * K + k0 + col8, &sA[ci * 512]);
      } else {
        int cj = ci - ACH;
        int row = cj * 8 + sub;
        async16(B + (size_t)(n0 + row) * K + k0 + col8, &sB[cj * 512]);
      }
    }
    __syncthreads();
#pragma unroll
    for (int kc = 0; kc < 2; ++kc) {
      bf16x8 af[AFR], bfv[BFR];
      const int ko = kc * 32 + khi * 8;
#pragma unroll
      for (int i = 0; i < AFR; ++i)
        af[i] = *(const bf16x8*)&sA[(wm + i * 16 + mlo) * 64 + ko];
#pragma unroll
      for (int j = 0; j < BFR; ++j)
        bfv[j] = *(const bf16x8*)&sB[(wn + j * 16 + mlo) * 64 + ko];
#pragma unroll
      for (int i = 0; i < AFR; ++i)
#pragma unroll
        for (int j = 0; j < BFR; ++j)
          acc[i][j] = __builtin_amdgcn_mfma_f32_16x16x32_bf16(af[i], bfv[j],
                                                              acc[i][j], 0, 0, 0);
    }
    __syncthreads();
  }

#pragma unroll
  for (int i = 0; i < AFR; ++i) {
    const int mb = m0 + wm + i * 16 + khi * 4;
#pragma unroll
    for (int j = 0; j < BFR; ++j) {
      const int n = n0 + wn + j * 16 + mlo;
#pragma unroll
      for (int r = 0; r < 4; ++r) {
        const int m = mb + r;
        float val = acc[i][j][r];
        if constexpr (MODE == 1) {
          if (m < M) D[(size_t)m * CD + n] = val + bias[n];
        } else {
          int b = n >> 12, hw = n & (HWD - 1);
          size_t addr = ((size_t)(b * CD + m)) * HWD + hw;
          D[addr] = val + bias[m] + xres[addr];
        }
      }
    }
  }
}

// ---------------------------------------------------------------------------
// Fused Q projection: qbf[m, :] = LN( xt[m,:] @ wq^T + bq + 0.05*pe(m) ) bf16
// Tile = 64 tokens x 512 channels (full N per block -> LN fusable).
// 4 waves, each 64x128; AFR=4, BFR=8; LDS 8K A + 64K B + 2K stats.
// ---------------------------------------------------------------------------
__global__ __launch_bounds__(256) void qgemm_ln(const bf16* __restrict__ A,
                                                const bf16* __restrict__ Bw,
                                                const float* __restrict__ bias,
                                                const float* __restrict__ g1,
                                                const float* __restrict__ b1,
                                                bf16* __restrict__ Y) {
  constexpr int TM = 64, KK = 512;
  constexpr int AFR = 4, BFR = 8;
  __shared__ bf16 sA[TM * 64];
  __shared__ bf16 sB[512 * 64];
  __shared__ float sStat[4][TM][2];
  const int tid = threadIdx.x, wave = tid >> 6, lane = tid & 63;
  const int m0 = blockIdx.x * TM;
  const int wn = wave * 128;
  const int sub = lane >> 3, col8 = (lane & 7) * 8;
  const int mlo = lane & 15, khi = lane >> 4;
  f32x4 acc[AFR][BFR] = {};

  for (int k0 = 0; k0 < KK; k0 += 64) {
    // 72 chunks of 8 rows x 64 cols: 8 for A, 64 for B -> 18 per wave
#pragma unroll
    for (int r = 0; r < 18; ++r) {
      int ci = wave * 18 + r;
      if (ci < 8) {
        int row = ci * 8 + sub;
        async16(A + (size_t)(m0 + row) * KK + k0 + col8, &sA[ci * 512]);
      } else {
        int cj = ci - 8;
        int row = cj * 8 + sub;
        async16(Bw + (size_t)row * KK + k0 + col8, &sB[cj * 512]);
      }
    }
    __syncthreads();
#pragma unroll
    for (int kc = 0; kc < 2; ++kc) {
      const int ko = kc * 32 + khi * 8;
      bf16x8 af[AFR], bfv[BFR];
#pragma unroll
      for (int i = 0; i < AFR; ++i)
        af[i] = *(const bf16x8*)&sA[(i * 16 + mlo) * 64 + ko];
#pragma unroll
      for (int j = 0; j < BFR; ++j)
        bfv[j] = *(const bf16x8*)&sB[(wn + j * 16 + mlo) * 64 + ko];
#pragma unroll
      for (int i = 0; i < AFR; ++i)
#pragma unroll
        for (int j = 0; j < BFR; ++j)
          acc[i][j] = __builtin_amdgcn_mfma_f32_16x16x32_bf16(af[i], bfv[j],
                                                              acc[i][j], 0, 0, 0);
    }
    __syncthreads();
  }

  // per-lane channel params for n = wn + j*16 + mlo
  float cb[8], cg[8], ct[8];
#pragma unroll
  for (int j = 0; j < 8; ++j) {
    int n = wn + j * 16 + mlo;
    cb[j] = bias[n];
    cg[j] = g1[n];
    ct[j] = b1[n];
  }

  // pass 1: add bias + posenc into acc, per-row partial stats -> LDS
#pragma unroll
  for (int i = 0; i < AFR; ++i) {
#pragma unroll
    for (int r = 0; r < 4; ++r) {
      const int row = i * 16 + khi * 4 + r;
      const int hw = (m0 + row) & (HWD - 1);
      const float pex = (float)(hw & 63) * (0.05f / 63.0f);
      const float pey = (float)(hw >> 6) * (0.05f / 63.0f);
      float s = 0.f, sq = 0.f;
#pragma unroll
      for (int j = 0; j < 8; ++j) {
        float v = acc[i][j][r] + cb[j] + ((wn + j * 16) < 256 ? pex : pey);
        acc[i][j][r] = v;
        s += v;
        sq += v * v;
      }
      // reduce across the 16 lanes of this khi group (all cols of this row
      // owned by this wave)
      s += __shfl_xor(s, 1);  sq += __shfl_xor(sq, 1);
      s += __shfl_xor(s, 2);  sq += __shfl_xor(sq, 2);
      s += __shfl_xor(s, 4);  sq += __shfl_xor(sq, 4);
      s += __shfl_xor(s, 8);  sq += __shfl_xor(sq, 8);
      if (mlo == 0) {
        sStat[wave][row][0] = s;
        sStat[wave][row][1] = sq;
      }
    }
  }
  __syncthreads();

  // pass 2: combine cross-wave stats, normalize, store bf16
#pragma unroll
  for (int i = 0; i < AFR; ++i) {
#pragma unroll
    for (int r = 0; r < 4; ++r) {
      const int row = i * 16 + khi * 4 + r;
      float s = sStat[0][row][0] + sStat[1][row][0] +
                sStat[2][row][0] + sStat[3][row][0];
      float sq = sStat[0][row][1] + sStat[1][row][1] +
                 sStat[2][row][1] + sStat[3][row][1];
      float mean = s * (1.0f / 512.0f);
      float var = sq * (1.0f / 512.0f) - mean * mean;
      float rstd = rsqrtf(var + 1e-5f);
      bf16* yr = Y + (size_t)(m0 + row) * CD + wn + mlo;
#pragma unroll
      for (int j = 0; j < 8; ++j)
        yr[j * 16] = (bf16)((acc[i][j][r] - mean) * rstd * cg[j] + ct[j]);
    }
  }
}

// ---------------------------------------------------------------------------
// LayerNorm over rows of 512 (wave per row) — k path only now.
// khlayout=1: Y = kh [B,NH,L,HD] bf16 (head-split)
// ---------------------------------------------------------------------------
__global__ __launch_bounds__(256) void ln_rows(const float* __restrict__ X,
                                               const float* __restrict__ gg,
                                               const float* __restrict__ bb,
                                               bf16* __restrict__ Y, int nrows,
                                               int khlayout) {
  const int wv = threadIdx.x >> 6, lane = threadIdx.x & 63;
  const int row = blockIdx.x * 4 + wv;
  if (row >= nrows) return;
  const float* xr = X + (size_t)row * CD + lane * 8;
  float4 v0 = *(const float4*)xr;
  float4 v1 = *(const float4*)(xr + 4);
  float xv[8] = {v0.x, v0.y, v0.z, v0.w, v1.x, v1.y, v1.z, v1.w};
  float s = 0.f, sq = 0.f;
#pragma unroll
  for (int j = 0; j < 8; ++j) { s += xv[j]; sq += xv[j] * xv[j]; }
#pragma unroll
  for (int off = 1; off < 64; off <<= 1) {
    s += __shfl_xor(s, off);
    sq += __shfl_xor(sq, off);
  }
  float mean = s * (1.0f / 512.0f);
  float var = sq * (1.0f / 512.0f) - mean * mean;
  float rstd = rsqrtf(var + 1e-5f);
  const int c0 = lane * 8;
  union { uint4 u; unsigned short us[8]; } pk;
#pragma unroll
  for (int j = 0; j < 8; ++j)
    pk.us[j] = bfb((xv[j] - mean) * rstd * gg[c0 + j] + bb[c0 + j]);
  size_t ya;
  if (khlayout) {
    int bq = row / LD, l = row - bq * LD;
    int hh = lane >> 3, dd = (lane & 7) * 8;
    ya = (((size_t)(bq * NH_ + hh)) * LD + l) * HD_ + dd;
  } else {
    ya = (size_t)row * CD + c0;
  }
  *(uint4*)(Y + ya) = pk.u;
}

// ---------------------------------------------------------------------------
// vraw [B*L, 512] fp32 -> vt [B*NH, HD, 96] bf16 (key dim transposed,
// cols 77..95 zero so PV K-loop can run over 96 with no masking)
// ---------------------------------------------------------------------------
__global__ __launch_bounds__(256) void make_vt(const float* __restrict__ vraw,
                                               bf16* __restrict__ vt) {
  const int bh = blockIdx.x, b = bh >> 3, h = bh & 7;
  const int tid = threadIdx.x, d = tid & 63, lg = tid >> 6;
  for (int l = lg; l < 96; l += 4) {
    float v = 0.f;
    if (l < LD) v = vraw[((size_t)(b * LD + l)) * CD + h * HD_ + d];
    vt[((size_t)(bh * HD_ + d)) * 96 + l] = (bf16)v;
  }
}

// ---------------------------------------------------------------------------
// Attention: block = (64 queries, head h, batch b); 4 waves x 16-query strips.
// S = Q K^T (MFMA), in-register softmax over 77 keys, P through LDS
// (C-layout -> A-layout), O = P V (MFMA, V pre-transposed & zero-padded).
// ---------------------------------------------------------------------------
__global__ __launch_bounds__(256) void attn_k(const bf16* __restrict__ Q,
                                              const bf16* __restrict__ KH,
                                              const bf16* __restrict__ VT,
                                              bf16* __restrict__ O) {
  __shared__ bf16 P[4][16 * 104];  // per-wave 16x96 P, stride 104 vs bank conflicts
  const int tid = threadIdx.x, wv = tid >> 6, lane = tid & 63;
  const int m = lane & 15, kg = lane >> 4;
  const int q0 = blockIdx.x * 64, h = blockIdx.y, b = blockIdx.z;
  const int bh = b * NH_ + h;

  // Q A-frags straight from global (read-once data)
  const size_t qoff = ((size_t)(b * HWD + q0 + wv * 16 + m)) * CD + h * HD_;
  bf16x8 a0 = *(const bf16x8*)(Q + qoff + kg * 8);
  bf16x8 a1 = *(const bf16x8*)(Q + qoff + 32 + kg * 8);

  // S = Q K^T : 5 key tiles of 16
  const bf16* Kb = KH + (size_t)bh * LD * HD_;
  f32x4 s[5];
#pragma unroll
  for (int kt = 0; kt < 5; ++kt) {
    int key = kt * 16 + m;
    if (key > LD - 1) key = LD - 1;  // clamped rows get masked below
    const bf16* kr = Kb + key * HD_ + kg * 8;
    bf16x8 b0 = *(const bf16x8*)kr;
    bf16x8 b1 = *(const bf16x8*)(kr + 32);
    f32x4 z = {0.f, 0.f, 0.f, 0.f};
    z = __builtin_amdgcn_mfma_f32_16x16x32_bf16(a0, b0, z, 0, 0, 0);
    z = __builtin_amdgcn_mfma_f32_16x16x32_bf16(a1, b1, z, 0, 0, 0);
    s[kt] = z;
  }

  // softmax per row (row = kg*4+r, cols live in lanes kg*16..kg*16+15)
  bf16* Pw = &P[wv][0];
#pragma unroll
  for (int r = 0; r < 4; ++r) {
    float sc[5];
#pragma unroll
    for (int kt = 0; kt < 5; ++kt) {
      float v = s[kt][r] * 0.125f;  // HD^-0.5
      if (kt == 4 && m >= LD - 64) v = -3.0e38f;
      sc[kt] = v;
    }
    float mx = fmaxf(fmaxf(fmaxf(sc[0], sc[1]), fmaxf(sc[2], sc[3])), sc[4]);
    mx = fmaxf(mx, __shfl_xor(mx, 1));
    mx = fmaxf(mx, __shfl_xor(mx, 2));
    mx = fmaxf(mx, __shfl_xor(mx, 4));
    mx = fmaxf(mx, __shfl_xor(mx, 8));
    float sum = 0.f;
#pragma unroll
    for (int kt = 0; kt < 5; ++kt) {
      sc[kt] = __expf(sc[kt] - mx);
      sum += sc[kt];
    }
    sum += __shfl_xor(sum, 1);
    sum += __shfl_xor(sum, 2);
    sum += __shfl_xor(sum, 4);
    sum += __shfl_xor(sum, 8);
    float inv = 1.0f / sum;
    const int prow = kg * 4 + r;
#pragma unroll
    for (int kt = 0; kt < 5; ++kt)
      Pw[prow * 104 + kt * 16 + m] = (bf16)(sc[kt] * inv);
    Pw[prow * 104 + 80 + m] = (bf16)0.f;  // zero pad cols 80..95
  }
  __syncthreads();

  // O = P V : A-frags from LDS P, B-frags from global vt (L2-resident)
  bf16x8 ap[3];
#pragma unroll
  for (int kc = 0; kc < 3; ++kc)
    ap[kc] = *(const bf16x8*)&Pw[m * 104 + kc * 32 + kg * 8];

  const bf16* Vb = VT + (size_t)bh * HD_ * 96;
  f32x4 o[4] = {};
#pragma unroll
  for (int nt = 0; nt < 4; ++nt) {
#pragma unroll
    for (int kc = 0; kc < 3; ++kc) {
      bf16x8 bv = *(const bf16x8*)(Vb + (nt * 16 + m) * 96 + kc * 32 + kg * 8);
      o[nt] = __builtin_amdgcn_mfma_f32_16x16x32_bf16(ap[kc], bv, o[nt], 0, 0, 0);
    }
  }
#pragma unroll
  for (int nt = 0; nt < 4; ++nt)
#pragma unroll
    for (int r = 0; r < 4; ++r) {
      const int row = b * HWD + q0 + wv * 16 + kg * 4 + r;
      O[(size_t)row * CD + h * HD_ + nt * 16 + m] = (bf16)(o[nt][r]);
    }
}

// ---------------------------------------------------------------------------
extern "C" void kernel_launch(void* const* d_in, const int* in_sizes, int n_in,
                              void* d_out, int out_size, void* d_ws, size_t ws_size,
                              hipStream_t stream) {
  const float* x    = (const float*)d_in[0];
  const float* text = (const float*)d_in[1];
  const float* wq   = (const float*)d_in[2];
  const float* bq   = (const float*)d_in[3];
  const float* wk   = (const float*)d_in[4];
  const float* bk   = (const float*)d_in[5];
  const float* wv   = (const float*)d_in[6];
  const float* bv   = (const float*)d_in[7];
  const float* wo   = (const float*)d_in[8];
  const float* bo   = (const float*)d_in[9];
  const float* g1   = (const float*)d_in[10];
  const float* b1   = (const float*)d_in[11];
  const float* g2   = (const float*)d_in[12];
  const float* b2   = (const float*)d_in[13];
  float* out = (float*)d_out;

  char* p = (char*)d_ws;
  auto alloc = [&](size_t bytes) {
    char* r = p;
    p += (bytes + 255) & ~(size_t)255;
    return r;
  };
  bf16* xt     = (bf16*)alloc((size_t)BD * HWD * CD * 2);
  bf16* attn_o = (bf16*)alloc((size_t)BD * HWD * CD * 2);
  bf16* textb  = (bf16*)alloc((size_t)BD * LD * DD * 2);
  bf16* wqb    = (bf16*)alloc((size_t)CD * CD * 2);
  bf16* wkb    = (bf16*)alloc((size_t)CD * DD * 2);
  bf16* wvb    = (bf16*)alloc((size_t)CD * DD * 2);
  bf16* wob    = (bf16*)alloc((size_t)CD * CD * 2);
  float* kraw  = (float*)alloc((size_t)BD * LD * CD * 4);
  float* vraw  = (float*)alloc((size_t)BD * LD * CD * 4);
  bf16* kh     = (bf16*)alloc((size_t)BD * NH_ * LD * HD_ * 2);
  bf16* vt     = (bf16*)alloc((size_t)BD * NH_ * HD_ * 96 * 2);
  // d_out doubles as bf16 normalized-q scratch until the final O-proj GEMM
  bf16* qbf = (bf16*)out;

  // 0: convert inputs
  xpose_cvt<<<dim3(HWD / 64, CD / 64, BD), 256, 0, stream>>>(x, xt);
  const int nt_ = BD * LD * DD;
  cvt_bf16_k<<<(nt_ / 8 + 255) / 256, 256, 0, stream>>>(text, textb, nt_);
  cvt_bf16_k<<<(CD * CD / 8 + 255) / 256, 256, 0, stream>>>(wq, wqb, CD * CD);
  cvt_bf16_k<<<(CD * DD / 8 + 255) / 256, 256, 0, stream>>>(wk, wkb, CD * DD);
  cvt_bf16_k<<<(CD * DD / 8 + 255) / 256, 256, 0, stream>>>(wv, wvb, CD * DD);
  cvt_bf16_k<<<(CD * CD / 8 + 255) / 256, 256, 0, stream>>>(wo, wob, CD * CD);

  // 1: K/V projections (M=1232 padded to 10 tiles), LN(k), V transpose
  gemm_bt<128, 128, 1><<<dim3(4, 10), 256, 0, stream>>>(
      textb, wkb, BD * LD, CD, DD, bk, nullptr, kraw);
  gemm_bt<128, 128, 1><<<dim3(4, 10), 256, 0, stream>>>(
      textb, wvb, BD * LD, CD, DD, bv, nullptr, vraw);
  ln_rows<<<(BD * LD + 3) / 4, 256, 0, stream>>>(kraw, g2, b2, kh, BD * LD, 1);
  make_vt<<<BD * NH_, 256, 0, stream>>>(vraw, vt);

  // 2: fused Q projection + bias + posenc + LayerNorm -> bf16 (no fp32 round-trip)
  qgemm_ln<<<dim3(BD * HWD / 64), 256, 0, stream>>>(xt, wqb, bq, g1, b1, qbf);

  // 3: attention
  attn_k<<<dim3(HWD / 64, NH_, BD), 256, 0, stream>>>(qbf, kh, vt, attn_o);

  // 4: output projection (+bias +residual), computed transposed for coalescing
  gemm_bt<256, 128, 3><<<dim3(512, 2), 256, 0, stream>>>(
      wob, attn_o, CD, BD * HWD, CD, bo, x, out);
}

// Round 2
// 581.435 us; speedup vs baseline: 1.0814x; 1.0510x over previous
//
#include <hip/hip_runtime.h>
#include <stdint.h>

// Problem constants
#define BD   16
#define CD   512
#define HD_  64
#define NH_  8
#define HWD  4096
#define LD   77
#define DD   768

typedef __bf16 bf16;
typedef bf16 bf16x8 __attribute__((ext_vector_type(8)));
typedef float f32x4 __attribute__((ext_vector_type(4)));

__device__ __forceinline__ void async16(const bf16* g, bf16* l) {
  __builtin_amdgcn_global_load_lds(
      (const __attribute__((address_space(1))) void*)g,
      (__attribute__((address_space(3))) void*)l, 16, 0, 0);
}

__device__ __forceinline__ unsigned short bfb(float f) {
  bf16 h = (bf16)f;
  return __builtin_bit_cast(unsigned short, h);
}

// ---------------------------------------------------------------------------
// K0a: transpose+convert x [B,C,HW] f32 -> xt [B*HW, C] bf16 (LDS tile xpose)
// ---------------------------------------------------------------------------
__global__ __launch_bounds__(256) void xpose_cvt(const float* __restrict__ X,
                                                 bf16* __restrict__ Y) {
  __shared__ float tile[64][68];
  const int b = blockIdx.z, c0 = blockIdx.y * 64, t0 = blockIdx.x * 64;
  const int tid = threadIdx.x;
  const float* Xb = X + ((size_t)b * CD + c0) * HWD + t0;
#pragma unroll
  for (int p = 0; p < 4; ++p) {
    int c = (tid >> 4) + p * 16;
    int t = (tid & 15) * 4;
    float4 v = *(const float4*)(Xb + (size_t)c * HWD + t);
    *(float4*)&tile[c][t] = v;
  }
  __syncthreads();
  int t = tid >> 2, cb = (tid & 3) * 16;
  union { uint4 u[2]; unsigned short us[16]; } pk;
#pragma unroll
  for (int j = 0; j < 16; ++j) pk.us[j] = bfb(tile[cb + j][t]);
  uint4* Yp = (uint4*)(Y + ((size_t)(b * HWD + t0 + t)) * CD + c0 + cb);
  Yp[0] = pk.u[0];
  Yp[1] = pk.u[1];
}

// ---------------------------------------------------------------------------
// K0b: all five f32 -> bf16 converts in ONE dispatch (segment sizes are
// compile-time multiples of 2048 elems -> no bounds checks anywhere).
// ---------------------------------------------------------------------------
__global__ __launch_bounds__(256) void cvt_all(
    const float* __restrict__ t, const float* __restrict__ q,
    const float* __restrict__ k, const float* __restrict__ v,
    const float* __restrict__ o, bf16* __restrict__ tb, bf16* __restrict__ qb,
    bf16* __restrict__ kb, bf16* __restrict__ vb, bf16* __restrict__ ob) {
  // blocks per segment: text 462, wq 128, wk 192, wv 192, wo 128
  int bid = blockIdx.x;
  const float* src;
  bf16* dst;
  if (bid < 462) { src = t; dst = tb; }
  else if (bid < 590) { src = q; dst = qb; bid -= 462; }
  else if (bid < 782) { src = k; dst = kb; bid -= 590; }
  else if (bid < 974) { src = v; dst = vb; bid -= 782; }
  else { src = o; dst = ob; bid -= 974; }
  int i = (bid * 256 + threadIdx.x) * 8;
  float4 a = *(const float4*)(src + i);
  float4 c = *(const float4*)(src + i + 4);
  union { uint4 u; unsigned short us[8]; } pk;
  pk.us[0] = bfb(a.x); pk.us[1] = bfb(a.y); pk.us[2] = bfb(a.z); pk.us[3] = bfb(a.w);
  pk.us[4] = bfb(c.x); pk.us[5] = bfb(c.y); pk.us[6] = bfb(c.z); pk.us[7] = bfb(c.w);
  *(uint4*)(dst + i) = pk.u;
}

// ---------------------------------------------------------------------------
// m97-style GEMM: D[M,N] = A[M,K] * B[N,K]^T (+ mode-specific epilogue)
// MODE 2: fused K/V proj. Logical N = 1024: blocks with n0>=512 switch to
//         (B2, bias2, D2) = V side. D fp32 [M,512] += bias[n]; rows guarded.
// MODE 3: O-proj, token-major. m = token, n = out-channel.
//         D = out[B,C,HW] fp32; float4 epilogue: += bo[n] + x residual.
// ---------------------------------------------------------------------------
template <int TM, int TN, int MODE>
__global__ __launch_bounds__(256)
void gemm_bt(const bf16* __restrict__ A, const bf16* __restrict__ B,
             int M, int N, int K,
             const float* __restrict__ bias, const float* __restrict__ xres,
             float* __restrict__ D,
             const bf16* __restrict__ B2, const float* __restrict__ bias2,
             float* __restrict__ D2) {
  constexpr int WM = TM / 2, WN = TN / 2;
  constexpr int AFR = WM / 16, BFR = WN / 16;
  constexpr int ACH = TM / 8, TCH = (TM + TN) / 8, WCH = TCH / 4;
  __shared__ bf16 sA[TM * 64];
  __shared__ bf16 sB[TN * 64];
  const int tid = threadIdx.x, wave = tid >> 6, lane = tid & 63;
  const int m0 = blockIdx.y * TM;
  int n0 = blockIdx.x * TN;
  if constexpr (MODE == 2) {
    if (n0 >= (N >> 1)) { B = B2; bias = bias2; D = D2; n0 -= (N >> 1); }
  }
  const int wm = (wave >> 1) * WM, wn = (wave & 1) * WN;
  const int sub = lane >> 3, col8 = (lane & 7) * 8;
  const int mlo = lane & 15, khi = lane >> 4;
  f32x4 acc[AFR][BFR] = {};

  for (int k0 = 0; k0 < K; k0 += 64) {
#pragma unroll
    for (int r = 0; r < WCH; ++r) {
      int ci = wave * WCH + r;
      if (ci < ACH) {
        int row = ci * 8 + sub;
        int g = m0 + row;
        if (g > M - 1) g = M - 1;  // clamp partial M-tiles (KV GEMM)
        async16(A + (size_t)g * K + k0 + col8, &sA[ci * 512]);
      } else {
        int cj = ci - ACH;
        int row = cj * 8 + sub;
        async16(B + (size_t)(n0 + row) * K + k0 + col8, &sB[cj * 512]);
      }
    }
    __syncthreads();
#pragma unroll
    for (int kc = 0; kc < 2; ++kc) {
      bf16x8 af[AFR], bfv[BFR];
      const int ko = kc * 32 + khi * 8;
#pragma unroll
      for (int i = 0; i < AFR; ++i)
        af[i] = *(const bf16x8*)&sA[(wm + i * 16 + mlo) * 64 + ko];
#pragma unroll
      for (int j = 0; j < BFR; ++j)
        bfv[j] = *(const bf16x8*)&sB[(wn + j * 16 + mlo) * 64 + ko];
#pragma unroll
      for (int i = 0; i < AFR; ++i)
#pragma unroll
        for (int j = 0; j < BFR; ++j)
          acc[i][j] = __builtin_amdgcn_mfma_f32_16x16x32_bf16(af[i], bfv[j],
                                                              acc[i][j], 0, 0, 0);
    }
    __syncthreads();
  }

  if constexpr (MODE == 3) {
    // token-major epilogue: r=0..3 are 4 consecutive hw for one channel n
    float bn[BFR];
#pragma unroll
    for (int j = 0; j < BFR; ++j) bn[j] = bias[n0 + wn + j * 16 + mlo];
#pragma unroll
    for (int i = 0; i < AFR; ++i) {
      const int m = m0 + wm + i * 16 + khi * 4;  // token (same b for whole tile)
      const int b = m >> 12, hw = m & (HWD - 1);
      const float* xr0 = xres + ((size_t)b * CD) * HWD + hw;
      float* d0 = D + ((size_t)b * CD) * HWD + hw;
#pragma unroll
      for (int j = 0; j < BFR; ++j) {
        const size_t off = (size_t)(n0 + wn + j * 16 + mlo) * HWD;
        float4 xr = *(const float4*)(xr0 + off);
        float4 ov;
        ov.x = acc[i][j][0] + bn[j] + xr.x;
        ov.y = acc[i][j][1] + bn[j] + xr.y;
        ov.z = acc[i][j][2] + bn[j] + xr.z;
        ov.w = acc[i][j][3] + bn[j] + xr.w;
        *(float4*)(d0 + off) = ov;
      }
    }
  } else {
#pragma unroll
    for (int i = 0; i < AFR; ++i) {
      const int mb = m0 + wm + i * 16 + khi * 4;
#pragma unroll
      for (int j = 0; j < BFR; ++j) {
        const int n = n0 + wn + j * 16 + mlo;
#pragma unroll
        for (int r = 0; r < 4; ++r) {
          const int m = mb + r;
          if (m < M) D[(size_t)m * CD + n] = acc[i][j][r] + bias[n];
        }
      }
    }
  }
}

// ---------------------------------------------------------------------------
// Fused Q projection: qbf[m, :] = LN( xt[m,:] @ wq^T + bq + 0.05*pe(m) ) bf16
// Tile = 64 tokens x 512 channels (full N per block -> LN fusable).
// ---------------------------------------------------------------------------
__global__ __launch_bounds__(256) void qgemm_ln(const bf16* __restrict__ A,
                                                const bf16* __restrict__ Bw,
                                                const float* __restrict__ bias,
                                                const float* __restrict__ g1,
                                                const float* __restrict__ b1,
                                                bf16* __restrict__ Y) {
  constexpr int TM = 64, KK = 512;
  constexpr int AFR = 4, BFR = 8;
  __shared__ bf16 sA[TM * 64];
  __shared__ bf16 sB[512 * 64];
  __shared__ float sStat[4][TM][2];
  const int tid = threadIdx.x, wave = tid >> 6, lane = tid & 63;
  const int m0 = blockIdx.x * TM;
  const int wn = wave * 128;
  const int sub = lane >> 3, col8 = (lane & 7) * 8;
  const int mlo = lane & 15, khi = lane >> 4;
  f32x4 acc[AFR][BFR] = {};

  for (int k0 = 0; k0 < KK; k0 += 64) {
#pragma unroll
    for (int r = 0; r < 18; ++r) {
      int ci = wave * 18 + r;
      if (ci < 8) {
        int row = ci * 8 + sub;
        async16(A + (size_t)(m0 + row) * KK + k0 + col8, &sA[ci * 512]);
      } else {
        int cj = ci - 8;
        int row = cj * 8 + sub;
        async16(Bw + (size_t)row * KK + k0 + col8, &sB[cj * 512]);
      }
    }
    __syncthreads();
#pragma unroll
    for (int kc = 0; kc < 2; ++kc) {
      const int ko = kc * 32 + khi * 8;
      bf16x8 af[AFR], bfv[BFR];
#pragma unroll
      for (int i = 0; i < AFR; ++i)
        af[i] = *(const bf16x8*)&sA[(i * 16 + mlo) * 64 + ko];
#pragma unroll
      for (int j = 0; j < BFR; ++j)
        bfv[j] = *(const bf16x8*)&sB[(wn + j * 16 + mlo) * 64 + ko];
#pragma unroll
      for (int i = 0; i < AFR; ++i)
#pragma unroll
        for (int j = 0; j < BFR; ++j)
          acc[i][j] = __builtin_amdgcn_mfma_f32_16x16x32_bf16(af[i], bfv[j],
                                                              acc[i][j], 0, 0, 0);
    }
    __syncthreads();
  }

  float cb[8], cg[8], ct[8];
#pragma unroll
  for (int j = 0; j < 8; ++j) {
    int n = wn + j * 16 + mlo;
    cb[j] = bias[n];
    cg[j] = g1[n];
    ct[j] = b1[n];
  }

  // pass 1: add bias + posenc into acc, per-row partial stats -> LDS
#pragma unroll
  for (int i = 0; i < AFR; ++i) {
#pragma unroll
    for (int r = 0; r < 4; ++r) {
      const int row = i * 16 + khi * 4 + r;
      const int hw = (m0 + row) & (HWD - 1);
      const float pex = (float)(hw & 63) * (0.05f / 63.0f);
      const float pey = (float)(hw >> 6) * (0.05f / 63.0f);
      float s = 0.f, sq = 0.f;
#pragma unroll
      for (int j = 0; j < 8; ++j) {
        float v = acc[i][j][r] + cb[j] + ((wn + j * 16) < 256 ? pex : pey);
        acc[i][j][r] = v;
        s += v;
        sq += v * v;
      }
      s += __shfl_xor(s, 1);  sq += __shfl_xor(sq, 1);
      s += __shfl_xor(s, 2);  sq += __shfl_xor(sq, 2);
      s += __shfl_xor(s, 4);  sq += __shfl_xor(sq, 4);
      s += __shfl_xor(s, 8);  sq += __shfl_xor(sq, 8);
      if (mlo == 0) {
        sStat[wave][row][0] = s;
        sStat[wave][row][1] = sq;
      }
    }
  }
  __syncthreads();

  // pass 2: combine cross-wave stats, normalize, store bf16
#pragma unroll
  for (int i = 0; i < AFR; ++i) {
#pragma unroll
    for (int r = 0; r < 4; ++r) {
      const int row = i * 16 + khi * 4 + r;
      float s = sStat[0][row][0] + sStat[1][row][0] +
                sStat[2][row][0] + sStat[3][row][0];
      float sq = sStat[0][row][1] + sStat[1][row][1] +
                 sStat[2][row][1] + sStat[3][row][1];
      float mean = s * (1.0f / 512.0f);
      float var = sq * (1.0f / 512.0f) - mean * mean;
      float rstd = rsqrtf(var + 1e-5f);
      bf16* yr = Y + (size_t)(m0 + row) * CD + wn + mlo;
#pragma unroll
      for (int j = 0; j < 8; ++j)
        yr[j * 16] = (bf16)((acc[i][j][r] - mean) * rstd * cg[j] + ct[j]);
    }
  }
}

// ---------------------------------------------------------------------------
// LayerNorm over rows of 512 (wave per row) — k path only.
// khlayout=1: Y = kh [B,NH,L,HD] bf16 (head-split)
// ---------------------------------------------------------------------------
__global__ __launch_bounds__(256) void ln_rows(const float* __restrict__ X,
                                               const float* __restrict__ gg,
                                               const float* __restrict__ bb,
                                               bf16* __restrict__ Y, int nrows,
                                               int khlayout) {
  const int wv = threadIdx.x >> 6, lane = threadIdx.x & 63;
  const int row = blockIdx.x * 4 + wv;
  if (row >= nrows) return;
  const float* xr = X + (size_t)row * CD + lane * 8;
  float4 v0 = *(const float4*)xr;
  float4 v1 = *(const float4*)(xr + 4);
  float xv[8] = {v0.x, v0.y, v0.z, v0.w, v1.x, v1.y, v1.z, v1.w};
  float s = 0.f, sq = 0.f;
#pragma unroll
  for (int j = 0; j < 8; ++j) { s += xv[j]; sq += xv[j] * xv[j]; }
#pragma unroll
  for (int off = 1; off < 64; off <<= 1) {
    s += __shfl_xor(s, off);
    sq += __shfl_xor(sq, off);
  }
  float mean = s * (1.0f / 512.0f);
  float var = sq * (1.0f / 512.0f) - mean * mean;
  float rstd = rsqrtf(var + 1e-5f);
  const int c0 = lane * 8;
  union { uint4 u; unsigned short us[8]; } pk;
#pragma unroll
  for (int j = 0; j < 8; ++j)
    pk.us[j] = bfb((xv[j] - mean) * rstd * gg[c0 + j] + bb[c0 + j]);
  size_t ya;
  if (khlayout) {
    int bq = row / LD, l = row - bq * LD;
    int hh = lane >> 3, dd = (lane & 7) * 8;
    ya = (((size_t)(bq * NH_ + hh)) * LD + l) * HD_ + dd;
  } else {
    ya = (size_t)row * CD + c0;
  }
  *(uint4*)(Y + ya) = pk.u;
}

// ---------------------------------------------------------------------------
// vraw [B*L, 512] fp32 -> vt [B*NH, HD, 96] bf16 (key dim transposed,
// cols 77..95 zero so PV K-loop can run over 96 with no masking)
// ---------------------------------------------------------------------------
__global__ __launch_bounds__(256) void make_vt(const float* __restrict__ vraw,
                                               bf16* __restrict__ vt) {
  const int bh = blockIdx.x, b = bh >> 3, h = bh & 7;
  const int tid = threadIdx.x, d = tid & 63, lg = tid >> 6;
  for (int l = lg; l < 96; l += 4) {
    float v = 0.f;
    if (l < LD) v = vraw[((size_t)(b * LD + l)) * CD + h * HD_ + d];
    vt[((size_t)(bh * HD_ + d)) * 96 + l] = (bf16)v;
  }
}

// ---------------------------------------------------------------------------
// Attention: block = (64 queries, head h, batch b); 4 waves x 16-query strips.
// ---------------------------------------------------------------------------
__global__ __launch_bounds__(256) void attn_k(const bf16* __restrict__ Q,
                                              const bf16* __restrict__ KH,
                                              const bf16* __restrict__ VT,
                                              bf16* __restrict__ O) {
  __shared__ bf16 P[4][16 * 104];  // per-wave 16x96 P, stride 104 vs bank conflicts
  const int tid = threadIdx.x, wv = tid >> 6, lane = tid & 63;
  const int m = lane & 15, kg = lane >> 4;
  const int q0 = blockIdx.x * 64, h = blockIdx.y, b = blockIdx.z;
  const int bh = b * NH_ + h;

  const size_t qoff = ((size_t)(b * HWD + q0 + wv * 16 + m)) * CD + h * HD_;
  bf16x8 a0 = *(const bf16x8*)(Q + qoff + kg * 8);
  bf16x8 a1 = *(const bf16x8*)(Q + qoff + 32 + kg * 8);

  const bf16* Kb = KH + (size_t)bh * LD * HD_;
  f32x4 s[5];
#pragma unroll
  for (int kt = 0; kt < 5; ++kt) {
    int key = kt * 16 + m;
    if (key > LD - 1) key = LD - 1;  // clamped rows get masked below
    const bf16* kr = Kb + key * HD_ + kg * 8;
    bf16x8 b0 = *(const bf16x8*)kr;
    bf16x8 b1 = *(const bf16x8*)(kr + 32);
    f32x4 z = {0.f, 0.f, 0.f, 0.f};
    z = __builtin_amdgcn_mfma_f32_16x16x32_bf16(a0, b0, z, 0, 0, 0);
    z = __builtin_amdgcn_mfma_f32_16x16x32_bf16(a1, b1, z, 0, 0, 0);
    s[kt] = z;
  }

  bf16* Pw = &P[wv][0];
#pragma unroll
  for (int r = 0; r < 4; ++r) {
    float sc[5];
#pragma unroll
    for (int kt = 0; kt < 5; ++kt) {
      float v = s[kt][r] * 0.125f;  // HD^-0.5
      if (kt == 4 && m >= LD - 64) v = -3.0e38f;
      sc[kt] = v;
    }
    float mx = fmaxf(fmaxf(fmaxf(sc[0], sc[1]), fmaxf(sc[2], sc[3])), sc[4]);
    mx = fmaxf(mx, __shfl_xor(mx, 1));
    mx = fmaxf(mx, __shfl_xor(mx, 2));
    mx = fmaxf(mx, __shfl_xor(mx, 4));
    mx = fmaxf(mx, __shfl_xor(mx, 8));
    float sum = 0.f;
#pragma unroll
    for (int kt = 0; kt < 5; ++kt) {
      sc[kt] = __expf(sc[kt] - mx);
      sum += sc[kt];
    }
    sum += __shfl_xor(sum, 1);
    sum += __shfl_xor(sum, 2);
    sum += __shfl_xor(sum, 4);
    sum += __shfl_xor(sum, 8);
    float inv = 1.0f / sum;
    const int prow = kg * 4 + r;
#pragma unroll
    for (int kt = 0; kt < 5; ++kt)
      Pw[prow * 104 + kt * 16 + m] = (bf16)(sc[kt] * inv);
    Pw[prow * 104 + 80 + m] = (bf16)0.f;  // zero pad cols 80..95
  }
  __syncthreads();

  bf16x8 ap[3];
#pragma unroll
  for (int kc = 0; kc < 3; ++kc)
    ap[kc] = *(const bf16x8*)&Pw[m * 104 + kc * 32 + kg * 8];

  const bf16* Vb = VT + (size_t)bh * HD_ * 96;
  f32x4 o[4] = {};
#pragma unroll
  for (int nt = 0; nt < 4; ++nt) {
#pragma unroll
    for (int kc = 0; kc < 3; ++kc) {
      bf16x8 bv = *(const bf16x8*)(Vb + (nt * 16 + m) * 96 + kc * 32 + kg * 8);
      o[nt] = __builtin_amdgcn_mfma_f32_16x16x32_bf16(ap[kc], bv, o[nt], 0, 0, 0);
    }
  }
#pragma unroll
  for (int nt = 0; nt < 4; ++nt)
#pragma unroll
    for (int r = 0; r < 4; ++r) {
      const int row = b * HWD + q0 + wv * 16 + kg * 4 + r;
      O[(size_t)row * CD + h * HD_ + nt * 16 + m] = (bf16)(o[nt][r]);
    }
}

// ---------------------------------------------------------------------------
extern "C" void kernel_launch(void* const* d_in, const int* in_sizes, int n_in,
                              void* d_out, int out_size, void* d_ws, size_t ws_size,
                              hipStream_t stream) {
  const float* x    = (const float*)d_in[0];
  const float* text = (const float*)d_in[1];
  const float* wq   = (const float*)d_in[2];
  const float* bq   = (const float*)d_in[3];
  const float* wk   = (const float*)d_in[4];
  const float* bk   = (const float*)d_in[5];
  const float* wv   = (const float*)d_in[6];
  const float* bv   = (const float*)d_in[7];
  const float* wo   = (const float*)d_in[8];
  const float* bo   = (const float*)d_in[9];
  const float* g1   = (const float*)d_in[10];
  const float* b1   = (const float*)d_in[11];
  const float* g2   = (const float*)d_in[12];
  const float* b2   = (const float*)d_in[13];
  float* out = (float*)d_out;

  char* p = (char*)d_ws;
  auto alloc = [&](size_t bytes) {
    char* r = p;
    p += (bytes + 255) & ~(size_t)255;
    return r;
  };
  bf16* xt     = (bf16*)alloc((size_t)BD * HWD * CD * 2);
  bf16* attn_o = (bf16*)alloc((size_t)BD * HWD * CD * 2);
  bf16* textb  = (bf16*)alloc((size_t)BD * LD * DD * 2);
  bf16* wqb    = (bf16*)alloc((size_t)CD * CD * 2);
  bf16* wkb    = (bf16*)alloc((size_t)CD * DD * 2);
  bf16* wvb    = (bf16*)alloc((size_t)CD * DD * 2);
  bf16* wob    = (bf16*)alloc((size_t)CD * CD * 2);
  float* kraw  = (float*)alloc((size_t)BD * LD * CD * 4);
  float* vraw  = (float*)alloc((size_t)BD * LD * CD * 4);
  bf16* kh     = (bf16*)alloc((size_t)BD * NH_ * LD * HD_ * 2);
  bf16* vt     = (bf16*)alloc((size_t)BD * NH_ * HD_ * 96 * 2);
  // d_out doubles as bf16 normalized-q scratch until the final O-proj GEMM
  bf16* qbf = (bf16*)out;

  // 0: convert inputs
  xpose_cvt<<<dim3(HWD / 64, CD / 64, BD), 256, 0, stream>>>(x, xt);
  cvt_all<<<1102, 256, 0, stream>>>(text, wq, wk, wv, wo,
                                    textb, wqb, wkb, wvb, wob);

  // 1: fused K+V projection (logical N=1024), LN(k), V transpose
  gemm_bt<128, 128, 2><<<dim3(8, 10), 256, 0, stream>>>(
      textb, wkb, BD * LD, 2 * CD, DD, bk, nullptr, kraw, wvb, bv, vraw);
  ln_rows<<<(BD * LD + 3) / 4, 256, 0, stream>>>(kraw, g2, b2, kh, BD * LD, 1);
  make_vt<<<BD * NH_, 256, 0, stream>>>(vraw, vt);

  // 2: fused Q projection + bias + posenc + LayerNorm -> bf16
  qgemm_ln<<<dim3(BD * HWD / 64), 256, 0, stream>>>(xt, wqb, bq, g1, b1, qbf);

  // 3: attention
  attn_k<<<dim3(HWD / 64, NH_, BD), 256, 0, stream>>>(qbf, kh, vt, attn_o);

  // 4: output projection, token-major (+bias +residual), float4 epilogue
  gemm_bt<256, 128, 3><<<dim3(CD / 128, BD * HWD / 256), 256, 0, stream>>>(
      attn_o, wob, BD * HWD, CD, CD, bo, x, out, nullptr, nullptr, nullptr);
}

// Round 3
// 557.650 us; speedup vs baseline: 1.1275x; 1.0427x over previous
//
#include <hip/hip_runtime.h>
#include <stdint.h>

// Problem constants
#define BD   16
#define CD   512
#define HD_  64
#define NH_  8
#define HWD  4096
#define LD   77
#define DD   768

typedef __bf16 bf16;
typedef bf16 bf16x8 __attribute__((ext_vector_type(8)));
typedef float f32x4 __attribute__((ext_vector_type(4)));

__device__ __forceinline__ void async16(const bf16* g, bf16* l) {
  __builtin_amdgcn_global_load_lds(
      (const __attribute__((address_space(1))) void*)g,
      (__attribute__((address_space(3))) void*)l, 16, 0, 0);
}

__device__ __forceinline__ unsigned short bfb(float f) {
  bf16 h = (bf16)f;
  return __builtin_bit_cast(unsigned short, h);
}

// ---------------------------------------------------------------------------
// K0a: transpose+convert x [B,C,HW] f32 -> xt [B*HW, C] bf16 (LDS tile xpose)
// ---------------------------------------------------------------------------
__global__ __launch_bounds__(256) void xpose_cvt(const float* __restrict__ X,
                                                 bf16* __restrict__ Y) {
  __shared__ float tile[64][68];
  const int b = blockIdx.z, c0 = blockIdx.y * 64, t0 = blockIdx.x * 64;
  const int tid = threadIdx.x;
  const float* Xb = X + ((size_t)b * CD + c0) * HWD + t0;
#pragma unroll
  for (int p = 0; p < 4; ++p) {
    int c = (tid >> 4) + p * 16;
    int t = (tid & 15) * 4;
    float4 v = *(const float4*)(Xb + (size_t)c * HWD + t);
    *(float4*)&tile[c][t] = v;
  }
  __syncthreads();
  int t = tid >> 2, cb = (tid & 3) * 16;
  union { uint4 u[2]; unsigned short us[16]; } pk;
#pragma unroll
  for (int j = 0; j < 16; ++j) pk.us[j] = bfb(tile[cb + j][t]);
  uint4* Yp = (uint4*)(Y + ((size_t)(b * HWD + t0 + t)) * CD + c0 + cb);
  Yp[0] = pk.u[0];
  Yp[1] = pk.u[1];
}

// ---------------------------------------------------------------------------
// K0b: all five f32 -> bf16 converts in ONE dispatch
// ---------------------------------------------------------------------------
__global__ __launch_bounds__(256) void cvt_all(
    const float* __restrict__ t, const float* __restrict__ q,
    const float* __restrict__ k, const float* __restrict__ v,
    const float* __restrict__ o, bf16* __restrict__ tb, bf16* __restrict__ qb,
    bf16* __restrict__ kb, bf16* __restrict__ vb, bf16* __restrict__ ob) {
  // blocks per segment: text 462, wq 128, wk 192, wv 192, wo 128
  int bid = blockIdx.x;
  const float* src;
  bf16* dst;
  if (bid < 462) { src = t; dst = tb; }
  else if (bid < 590) { src = q; dst = qb; bid -= 462; }
  else if (bid < 782) { src = k; dst = kb; bid -= 590; }
  else if (bid < 974) { src = v; dst = vb; bid -= 782; }
  else { src = o; dst = ob; bid -= 974; }
  int i = (bid * 256 + threadIdx.x) * 8;
  float4 a = *(const float4*)(src + i);
  float4 c = *(const float4*)(src + i + 4);
  union { uint4 u; unsigned short us[8]; } pk;
  pk.us[0] = bfb(a.x); pk.us[1] = bfb(a.y); pk.us[2] = bfb(a.z); pk.us[3] = bfb(a.w);
  pk.us[4] = bfb(c.x); pk.us[5] = bfb(c.y); pk.us[6] = bfb(c.z); pk.us[7] = bfb(c.w);
  *(uint4*)(dst + i) = pk.u;
}

// ---------------------------------------------------------------------------
// m97-style GEMM: D[M,N] = A[M,K] * B[N,K]^T, flat 1D grid with bijective
// XCD swizzle (gridDim.x % 8 == 0 guaranteed by all launches).
// MODE 0: Q-proj. Epilogue: += bq[n] + 0.05*pe; round to bf16, store to
//         Dq=(bf16*)D; per-row partial (sum,sumsq) of rounded values ->
//         pstat[(n0/128)*65536 + m] (float2, via xres arg). LN applied later
//         in attn_k.
// MODE 2: fused K/V proj. Logical N = 1024: blocks with n0>=512 switch to
//         (B2, bias2, D2) = V side. D fp32 [M,512] += bias[n]; rows guarded.
// MODE 3: O-proj, token-major. m = token, n = out-channel.
//         D = out[B,C,HW] fp32; float4 epilogue: += bo[n] + x residual.
// ---------------------------------------------------------------------------
template <int TM, int TN, int MODE, int NBX>
__global__ __launch_bounds__(256)
void gemm_bt(const bf16* __restrict__ A, const bf16* __restrict__ B,
             int M, int N, int K,
             const float* __restrict__ bias, const float* __restrict__ xres,
             float* __restrict__ D,
             const bf16* __restrict__ B2, const float* __restrict__ bias2,
             float* __restrict__ D2) {
  constexpr int WM = TM / 2, WN = TN / 2;
  constexpr int AFR = WM / 16, BFR = WN / 16;
  constexpr int ACH = TM / 8, TCH = (TM + TN) / 8, WCH = TCH / 4;
  __shared__ bf16 sA[TM * 64];
  __shared__ bf16 sB[TN * 64];
  const int tid = threadIdx.x, wave = tid >> 6, lane = tid & 63;
  // bijective XCD swizzle: XCD i gets a contiguous chunk of tile-space
  int flat = blockIdx.x;
  {
    const int qq = (int)gridDim.x >> 3;
    flat = (flat & 7) * qq + (flat >> 3);
  }
  const int m0 = (flat / NBX) * TM;
  int n0 = (flat % NBX) * TN;
  if constexpr (MODE == 2) {
    if (n0 >= (N >> 1)) { B = B2; bias = bias2; D = D2; n0 -= (N >> 1); }
  }
  const int wm = (wave >> 1) * WM, wn = (wave & 1) * WN;
  const int sub = lane >> 3, col8 = (lane & 7) * 8;
  const int mlo = lane & 15, khi = lane >> 4;
  f32x4 acc[AFR][BFR] = {};

  for (int k0 = 0; k0 < K; k0 += 64) {
#pragma unroll
    for (int r = 0; r < WCH; ++r) {
      int ci = wave * WCH + r;
      if (ci < ACH) {
        int row = ci * 8 + sub;
        int g = m0 + row;
        if (g > M - 1) g = M - 1;  // clamp partial M-tiles (KV GEMM)
        async16(A + (size_t)g * K + k0 + col8, &sA[ci * 512]);
      } else {
        int cj = ci - ACH;
        int row = cj * 8 + sub;
        async16(B + (size_t)(n0 + row) * K + k0 + col8, &sB[cj * 512]);
      }
    }
    __syncthreads();
#pragma unroll
    for (int kc = 0; kc < 2; ++kc) {
      bf16x8 af[AFR], bfv[BFR];
      const int ko = kc * 32 + khi * 8;
#pragma unroll
      for (int i = 0; i < AFR; ++i)
        af[i] = *(const bf16x8*)&sA[(wm + i * 16 + mlo) * 64 + ko];
#pragma unroll
      for (int j = 0; j < BFR; ++j)
        bfv[j] = *(const bf16x8*)&sB[(wn + j * 16 + mlo) * 64 + ko];
#pragma unroll
      for (int i = 0; i < AFR; ++i)
#pragma unroll
        for (int j = 0; j < BFR; ++j)
          acc[i][j] = __builtin_amdgcn_mfma_f32_16x16x32_bf16(af[i], bfv[j],
                                                              acc[i][j], 0, 0, 0);
    }
    __syncthreads();
  }

  if constexpr (MODE == 0) {
    // Q-proj epilogue: bias + posenc, bf16 round, store, partial row stats
    __shared__ float sRS[TM][2][2];
    bf16* Dq = (bf16*)D;
    const int wnh = wave & 1;
#pragma unroll
    for (int i = 0; i < AFR; ++i) {
#pragma unroll
      for (int r = 0; r < 4; ++r) {
        const int rowt = wm + i * 16 + khi * 4 + r;
        const int m = m0 + rowt;
        const int hw = m & (HWD - 1);
        const float pex = (float)(hw & 63) * (0.05f / 63.0f);
        const float pey = (float)(hw >> 6) * (0.05f / 63.0f);
        float s = 0.f, sq = 0.f;
#pragma unroll
        for (int j = 0; j < BFR; ++j) {
          const int n = n0 + wn + j * 16 + mlo;
          float v = acc[i][j][r] + bias[n] + (n < 256 ? pex : pey);
          bf16 hv = (bf16)v;
          Dq[(size_t)m * CD + n] = hv;
          float vr = (float)hv;
          s += vr;
          sq += vr * vr;
        }
        s += __shfl_xor(s, 1); sq += __shfl_xor(sq, 1);
        s += __shfl_xor(s, 2); sq += __shfl_xor(sq, 2);
        s += __shfl_xor(s, 4); sq += __shfl_xor(sq, 4);
        s += __shfl_xor(s, 8); sq += __shfl_xor(sq, 8);
        if (mlo == 0) { sRS[rowt][wnh][0] = s; sRS[rowt][wnh][1] = sq; }
      }
    }
    __syncthreads();
    if (tid < TM) {
      float s = sRS[tid][0][0] + sRS[tid][1][0];
      float sq = sRS[tid][0][1] + sRS[tid][1][1];
      float2* pst = (float2*)xres;
      pst[(size_t)(n0 >> 7) * (BD * HWD) + (m0 + tid)] = make_float2(s, sq);
    }
  } else if constexpr (MODE == 3) {
    // token-major epilogue: r=0..3 are 4 consecutive hw for one channel n
    float bn[BFR];
#pragma unroll
    for (int j = 0; j < BFR; ++j) bn[j] = bias[n0 + wn + j * 16 + mlo];
#pragma unroll
    for (int i = 0; i < AFR; ++i) {
      const int m = m0 + wm + i * 16 + khi * 4;  // token (same b for whole tile)
      const int b = m >> 12, hw = m & (HWD - 1);
      const float* xr0 = xres + ((size_t)b * CD) * HWD + hw;
      float* d0 = D + ((size_t)b * CD) * HWD + hw;
#pragma unroll
      for (int j = 0; j < BFR; ++j) {
        const size_t off = (size_t)(n0 + wn + j * 16 + mlo) * HWD;
        float4 xr = *(const float4*)(xr0 + off);
        float4 ov;
        ov.x = acc[i][j][0] + bn[j] + xr.x;
        ov.y = acc[i][j][1] + bn[j] + xr.y;
        ov.z = acc[i][j][2] + bn[j] + xr.z;
        ov.w = acc[i][j][3] + bn[j] + xr.w;
        *(float4*)(d0 + off) = ov;
      }
    }
  } else {
#pragma unroll
    for (int i = 0; i < AFR; ++i) {
      const int mb = m0 + wm + i * 16 + khi * 4;
#pragma unroll
      for (int j = 0; j < BFR; ++j) {
        const int n = n0 + wn + j * 16 + mlo;
#pragma unroll
        for (int r = 0; r < 4; ++r) {
          const int m = mb + r;
          if (m < M) D[(size_t)m * CD + n] = acc[i][j][r] + bias[n];
        }
      }
    }
  }
}

// ---------------------------------------------------------------------------
// LayerNorm over rows of 512 (wave per row) — k path only.
// khlayout=1: Y = kh [B,NH,L,HD] bf16 (head-split)
// ---------------------------------------------------------------------------
__global__ __launch_bounds__(256) void ln_rows(const float* __restrict__ X,
                                               const float* __restrict__ gg,
                                               const float* __restrict__ bb,
                                               bf16* __restrict__ Y, int nrows,
                                               int khlayout) {
  const int wv = threadIdx.x >> 6, lane = threadIdx.x & 63;
  const int row = blockIdx.x * 4 + wv;
  if (row >= nrows) return;
  const float* xr = X + (size_t)row * CD + lane * 8;
  float4 v0 = *(const float4*)xr;
  float4 v1 = *(const float4*)(xr + 4);
  float xv[8] = {v0.x, v0.y, v0.z, v0.w, v1.x, v1.y, v1.z, v1.w};
  float s = 0.f, sq = 0.f;
#pragma unroll
  for (int j = 0; j < 8; ++j) { s += xv[j]; sq += xv[j] * xv[j]; }
#pragma unroll
  for (int off = 1; off < 64; off <<= 1) {
    s += __shfl_xor(s, off);
    sq += __shfl_xor(sq, off);
  }
  float mean = s * (1.0f / 512.0f);
  float var = sq * (1.0f / 512.0f) - mean * mean;
  float rstd = rsqrtf(var + 1e-5f);
  const int c0 = lane * 8;
  union { uint4 u; unsigned short us[8]; } pk;
#pragma unroll
  for (int j = 0; j < 8; ++j)
    pk.us[j] = bfb((xv[j] - mean) * rstd * gg[c0 + j] + bb[c0 + j]);
  size_t ya;
  if (khlayout) {
    int bq = row / LD, l = row - bq * LD;
    int hh = lane >> 3, dd = (lane & 7) * 8;
    ya = (((size_t)(bq * NH_ + hh)) * LD + l) * HD_ + dd;
  } else {
    ya = (size_t)row * CD + c0;
  }
  *(uint4*)(Y + ya) = pk.u;
}

// ---------------------------------------------------------------------------
// vraw [B*L, 512] fp32 -> vt [B*NH, HD, 96] bf16 (key dim transposed,
// cols 77..95 zero so PV K-loop can run over 96 with no masking)
// ---------------------------------------------------------------------------
__global__ __launch_bounds__(256) void make_vt(const float* __restrict__ vraw,
                                               bf16* __restrict__ vt) {
  const int bh = blockIdx.x, b = bh >> 3, h = bh & 7;
  const int tid = threadIdx.x, d = tid & 63, lg = tid >> 6;
  for (int l = lg; l < 96; l += 4) {
    float v = 0.f;
    if (l < LD) v = vraw[((size_t)(b * LD + l)) * CD + h * HD_ + d];
    vt[((size_t)(bh * HD_ + d)) * 96 + l] = (bf16)v;
  }
}

// ---------------------------------------------------------------------------
// Attention: block = (64 queries, head h, batch b); 4 waves x 16-query strips.
// Q arrives pre-LN (bf16, bias+pe included); LN applied in-register here
// using per-row partial stats from the Q-GEMM (pstat: 4 x float2 per row).
// ---------------------------------------------------------------------------
__global__ __launch_bounds__(256) void attn_k(const bf16* __restrict__ Q,
                                              const float2* __restrict__ PST,
                                              const float* __restrict__ G1,
                                              const float* __restrict__ B1,
                                              const bf16* __restrict__ KH,
                                              const bf16* __restrict__ VT,
                                              bf16* __restrict__ O) {
  __shared__ bf16 P[4][16 * 104];  // per-wave 16x96 P, stride 104 vs bank conflicts
  const int tid = threadIdx.x, wv = tid >> 6, lane = tid & 63;
  const int m = lane & 15, kg = lane >> 4;
  const int q0 = blockIdx.x * 64, h = blockIdx.y, b = blockIdx.z;
  const int bh = b * NH_ + h;

  // raw (pre-LN) Q fragments
  const int rowg = b * HWD + q0 + wv * 16 + m;
  const size_t qoff = (size_t)rowg * CD + h * HD_;
  bf16x8 a0r = *(const bf16x8*)(Q + qoff + kg * 8);
  bf16x8 a1r = *(const bf16x8*)(Q + qoff + 32 + kg * 8);

  // combine the 4 per-nblock partial stats (one per kg lane-group)
  float2 st = PST[(size_t)kg * (BD * HWD) + rowg];
  float s = st.x, sq = st.y;
  s += __shfl_xor(s, 16); sq += __shfl_xor(sq, 16);
  s += __shfl_xor(s, 32); sq += __shfl_xor(sq, 32);
  const float mean = s * (1.0f / 512.0f);
  const float var = sq * (1.0f / 512.0f) - mean * mean;
  const float rstd = rsqrtf(var + 1e-5f);

  // per-lane LN params for channels c0..c0+7 and c0+32..c0+39
  const int c0 = h * HD_ + kg * 8;
  float4 ga = *(const float4*)(G1 + c0), gb = *(const float4*)(G1 + c0 + 4);
  float4 gc = *(const float4*)(G1 + c0 + 32), gd = *(const float4*)(G1 + c0 + 36);
  float4 ta = *(const float4*)(B1 + c0), tb = *(const float4*)(B1 + c0 + 4);
  float4 tc = *(const float4*)(B1 + c0 + 32), td = *(const float4*)(B1 + c0 + 36);
  const float gg[16] = {ga.x, ga.y, ga.z, ga.w, gb.x, gb.y, gb.z, gb.w,
                        gc.x, gc.y, gc.z, gc.w, gd.x, gd.y, gd.z, gd.w};
  const float bbv[16] = {ta.x, ta.y, ta.z, ta.w, tb.x, tb.y, tb.z, tb.w,
                         tc.x, tc.y, tc.z, tc.w, td.x, td.y, td.z, td.w};
  bf16x8 a0, a1;
#pragma unroll
  for (int e = 0; e < 8; ++e) {
    a0[e] = (bf16)(((float)a0r[e] - mean) * rstd * gg[e] + bbv[e]);
    a1[e] = (bf16)(((float)a1r[e] - mean) * rstd * gg[8 + e] + bbv[8 + e]);
  }

  // S = Q K^T : 5 key tiles of 16
  const bf16* Kb = KH + (size_t)bh * LD * HD_;
  f32x4 sacc[5];
#pragma unroll
  for (int kt = 0; kt < 5; ++kt) {
    int key = kt * 16 + m;
    if (key > LD - 1) key = LD - 1;  // clamped rows get masked below
    const bf16* kr = Kb + key * HD_ + kg * 8;
    bf16x8 b0 = *(const bf16x8*)kr;
    bf16x8 b1 = *(const bf16x8*)(kr + 32);
    f32x4 z = {0.f, 0.f, 0.f, 0.f};
    z = __builtin_amdgcn_mfma_f32_16x16x32_bf16(a0, b0, z, 0, 0, 0);
    z = __builtin_amdgcn_mfma_f32_16x16x32_bf16(a1, b1, z, 0, 0, 0);
    sacc[kt] = z;
  }

  // softmax per row (row = kg*4+r, cols live in lanes kg*16..kg*16+15)
  bf16* Pw = &P[wv][0];
#pragma unroll
  for (int r = 0; r < 4; ++r) {
    float sc[5];
#pragma unroll
    for (int kt = 0; kt < 5; ++kt) {
      float v = sacc[kt][r] * 0.125f;  // HD^-0.5
      if (kt == 4 && m >= LD - 64) v = -3.0e38f;
      sc[kt] = v;
    }
    float mx = fmaxf(fmaxf(fmaxf(sc[0], sc[1]), fmaxf(sc[2], sc[3])), sc[4]);
    mx = fmaxf(mx, __shfl_xor(mx, 1));
    mx = fmaxf(mx, __shfl_xor(mx, 2));
    mx = fmaxf(mx, __shfl_xor(mx, 4));
    mx = fmaxf(mx, __shfl_xor(mx, 8));
    float sum = 0.f;
#pragma unroll
    for (int kt = 0; kt < 5; ++kt) {
      sc[kt] = __expf(sc[kt] - mx);
      sum += sc[kt];
    }
    sum += __shfl_xor(sum, 1);
    sum += __shfl_xor(sum, 2);
    sum += __shfl_xor(sum, 4);
    sum += __shfl_xor(sum, 8);
    float inv = 1.0f / sum;
    const int prow = kg * 4 + r;
#pragma unroll
    for (int kt = 0; kt < 5; ++kt)
      Pw[prow * 104 + kt * 16 + m] = (bf16)(sc[kt] * inv);
    Pw[prow * 104 + 80 + m] = (bf16)0.f;  // zero pad cols 80..95
  }
  __syncthreads();

  // O = P V : A-frags from LDS P, B-frags from global vt (L2-resident)
  bf16x8 ap[3];
#pragma unroll
  for (int kc = 0; kc < 3; ++kc)
    ap[kc] = *(const bf16x8*)&Pw[m * 104 + kc * 32 + kg * 8];

  const bf16* Vb = VT + (size_t)bh * HD_ * 96;
  f32x4 o[4] = {};
#pragma unroll
  for (int nt = 0; nt < 4; ++nt) {
#pragma unroll
    for (int kc = 0; kc < 3; ++kc) {
      bf16x8 bv = *(const bf16x8*)(Vb + (nt * 16 + m) * 96 + kc * 32 + kg * 8);
      o[nt] = __builtin_amdgcn_mfma_f32_16x16x32_bf16(ap[kc], bv, o[nt], 0, 0, 0);
    }
  }
#pragma unroll
  for (int nt = 0; nt < 4; ++nt)
#pragma unroll
    for (int r = 0; r < 4; ++r) {
      const int row = b * HWD + q0 + wv * 16 + kg * 4 + r;
      O[(size_t)row * CD + h * HD_ + nt * 16 + m] = (bf16)(o[nt][r]);
    }
}

// ---------------------------------------------------------------------------
extern "C" void kernel_launch(void* const* d_in, const int* in_sizes, int n_in,
                              void* d_out, int out_size, void* d_ws, size_t ws_size,
                              hipStream_t stream) {
  const float* x    = (const float*)d_in[0];
  const float* text = (const float*)d_in[1];
  const float* wq   = (const float*)d_in[2];
  const float* bq   = (const float*)d_in[3];
  const float* wk   = (const float*)d_in[4];
  const float* bk   = (const float*)d_in[5];
  const float* wv   = (const float*)d_in[6];
  const float* bv   = (const float*)d_in[7];
  const float* wo   = (const float*)d_in[8];
  const float* bo   = (const float*)d_in[9];
  const float* g1   = (const float*)d_in[10];
  const float* b1   = (const float*)d_in[11];
  const float* g2   = (const float*)d_in[12];
  const float* b2   = (const float*)d_in[13];
  float* out = (float*)d_out;

  char* p = (char*)d_ws;
  auto alloc = [&](size_t bytes) {
    char* r = p;
    p += (bytes + 255) & ~(size_t)255;
    return r;
  };
  bf16* xt     = (bf16*)alloc((size_t)BD * HWD * CD * 2);
  bf16* attn_o = (bf16*)alloc((size_t)BD * HWD * CD * 2);
  bf16* textb  = (bf16*)alloc((size_t)BD * LD * DD * 2);
  bf16* wqb    = (bf16*)alloc((size_t)CD * CD * 2);
  bf16* wkb    = (bf16*)alloc((size_t)CD * DD * 2);
  bf16* wvb    = (bf16*)alloc((size_t)CD * DD * 2);
  bf16* wob    = (bf16*)alloc((size_t)CD * CD * 2);
  float* kraw  = (float*)alloc((size_t)BD * LD * CD * 4);
  float* vraw  = (float*)alloc((size_t)BD * LD * CD * 4);
  bf16* kh     = (bf16*)alloc((size_t)BD * NH_ * LD * HD_ * 2);
  bf16* vt     = (bf16*)alloc((size_t)BD * NH_ * HD_ * 96 * 2);
  float* pstat = (float*)alloc((size_t)4 * BD * HWD * 2 * 4);  // 4 nblk x row x {s,sq}
  // d_out doubles as bf16 pre-LN q scratch until the final O-proj GEMM
  bf16* qbf = (bf16*)out;

  // 0: convert inputs
  xpose_cvt<<<dim3(HWD / 64, CD / 64, BD), 256, 0, stream>>>(x, xt);
  cvt_all<<<1102, 256, 0, stream>>>(text, wq, wk, wv, wo,
                                    textb, wqb, wkb, wvb, wob);

  // 1: fused K+V projection (logical N=1024), LN(k), V transpose
  gemm_bt<128, 128, 2, 8><<<80, 256, 0, stream>>>(
      textb, wkb, BD * LD, 2 * CD, DD, bk, nullptr, kraw, wvb, bv, vraw);
  ln_rows<<<(BD * LD + 3) / 4, 256, 0, stream>>>(kraw, g2, b2, kh, BD * LD, 1);
  make_vt<<<BD * NH_, 256, 0, stream>>>(vraw, vt);

  // 2: Q projection (+bias+posenc), bf16 out + partial row stats (LN in attn)
  gemm_bt<128, 128, 0, 4><<<2048, 256, 0, stream>>>(
      xt, wqb, BD * HWD, CD, CD, bq, pstat, (float*)qbf,
      nullptr, nullptr, nullptr);

  // 3: attention (applies LN(q) in-register from pstat)
  attn_k<<<dim3(HWD / 64, NH_, BD), 256, 0, stream>>>(
      qbf, (const float2*)pstat, g1, b1, kh, vt, attn_o);

  // 4: output projection, token-major (+bias +residual), float4 epilogue
  gemm_bt<128, 128, 3, 4><<<2048, 256, 0, stream>>>(
      attn_o, wob, BD * HWD, CD, CD, bo, x, out, nullptr, nullptr, nullptr);
}

// Round 4
// 539.531 us; speedup vs baseline: 1.1654x; 1.0336x over previous
//
#include <hip/hip_runtime.h>
#include <stdint.h>

// Problem constants
#define BD   16
#define CD   512
#define HD_  64
#define NH_  8
#define HWD  4096
#define LD   77
#define DD   768

typedef __bf16 bf16;
typedef bf16 bf16x8 __attribute__((ext_vector_type(8)));
typedef float f32x4 __attribute__((ext_vector_type(4)));

__device__ __forceinline__ void async16(const bf16* g, bf16* l) {
  __builtin_amdgcn_global_load_lds(
      (const __attribute__((address_space(1))) void*)g,
      (__attribute__((address_space(3))) void*)l, 16, 0, 0);
}

__device__ __forceinline__ unsigned short bfb(float f) {
  bf16 h = (bf16)f;
  return __builtin_bit_cast(unsigned short, h);
}

// ---------------------------------------------------------------------------
// K0a: transpose+convert x [B,C,HW] f32 -> xt [B*HW, C] bf16 (LDS tile xpose)
// ---------------------------------------------------------------------------
__global__ __launch_bounds__(256) void xpose_cvt(const float* __restrict__ X,
                                                 bf16* __restrict__ Y) {
  __shared__ float tile[64][68];
  const int b = blockIdx.z, c0 = blockIdx.y * 64, t0 = blockIdx.x * 64;
  const int tid = threadIdx.x;
  const float* Xb = X + ((size_t)b * CD + c0) * HWD + t0;
#pragma unroll
  for (int p = 0; p < 4; ++p) {
    int c = (tid >> 4) + p * 16;
    int t = (tid & 15) * 4;
    float4 v = *(const float4*)(Xb + (size_t)c * HWD + t);
    *(float4*)&tile[c][t] = v;
  }
  __syncthreads();
  int t = tid >> 2, cb = (tid & 3) * 16;
  union { uint4 u[2]; unsigned short us[16]; } pk;
#pragma unroll
  for (int j = 0; j < 16; ++j) pk.us[j] = bfb(tile[cb + j][t]);
  uint4* Yp = (uint4*)(Y + ((size_t)(b * HWD + t0 + t)) * CD + c0 + cb);
  Yp[0] = pk.u[0];
  Yp[1] = pk.u[1];
}

// ---------------------------------------------------------------------------
// K0b: all five f32 -> bf16 converts in ONE dispatch
// ---------------------------------------------------------------------------
__global__ __launch_bounds__(256) void cvt_all(
    const float* __restrict__ t, const float* __restrict__ q,
    const float* __restrict__ k, const float* __restrict__ v,
    const float* __restrict__ o, bf16* __restrict__ tb, bf16* __restrict__ qb,
    bf16* __restrict__ kb, bf16* __restrict__ vb, bf16* __restrict__ ob) {
  // blocks per segment: text 462, wq 128, wk 192, wv 192, wo 128
  int bid = blockIdx.x;
  const float* src;
  bf16* dst;
  if (bid < 462) { src = t; dst = tb; }
  else if (bid < 590) { src = q; dst = qb; bid -= 462; }
  else if (bid < 782) { src = k; dst = kb; bid -= 590; }
  else if (bid < 974) { src = v; dst = vb; bid -= 782; }
  else { src = o; dst = ob; bid -= 974; }
  int i = (bid * 256 + threadIdx.x) * 8;
  float4 a = *(const float4*)(src + i);
  float4 c = *(const float4*)(src + i + 4);
  union { uint4 u; unsigned short us[8]; } pk;
  pk.us[0] = bfb(a.x); pk.us[1] = bfb(a.y); pk.us[2] = bfb(a.z); pk.us[3] = bfb(a.w);
  pk.us[4] = bfb(c.x); pk.us[5] = bfb(c.y); pk.us[6] = bfb(c.z); pk.us[7] = bfb(c.w);
  *(uint4*)(dst + i) = pk.u;
}

// ---------------------------------------------------------------------------
// m97-style GEMM + counted-vmcnt double-buffer prefetch (T3/T4 minimum form):
// two LDS buffers; tile t+2 is staged into buf[t&1] right after the barrier
// that releases it; steady-state wait is vmcnt(8) (next tile's 8 loads),
// NEVER vmcnt(0) in the main loop -> loads stay in flight across barriers.
// D[M,N] = A[M,K] * B[N,K]^T, flat 1D grid, bijective XCD swizzle.
// MODE 0: Q-proj. Epilogue: += bq[n] + 0.05*pe; round bf16 -> Dq; partial
//         row stats -> pstat[(n0/128)*65536 + m]. LN applied in attn_k.
// MODE 2: fused K/V proj (logical N=1024; upper half switches to V side).
// MODE 3: O-proj, token-major; float4 epilogue += bo[n] + x residual.
// ---------------------------------------------------------------------------
template <int TM, int TN, int MODE, int NBX>
__global__ __launch_bounds__(256)
void gemm_bt(const bf16* __restrict__ A, const bf16* __restrict__ B,
             int M, int N, int K,
             const float* __restrict__ bias, const float* __restrict__ xres,
             float* __restrict__ D,
             const bf16* __restrict__ B2, const float* __restrict__ bias2,
             float* __restrict__ D2) {
  constexpr int WM = TM / 2, WN = TN / 2;
  constexpr int AFR = WM / 16, BFR = WN / 16;
  constexpr int ACH = TM / 8, TCH = (TM + TN) / 8, WCH = TCH / 4;
  static_assert(WCH == 8, "vmcnt(8) literal assumes 8 loads/wave/tile");
  __shared__ bf16 sA[2][TM * 64];
  __shared__ bf16 sB[2][TN * 64];
  const int tid = threadIdx.x, wave = tid >> 6, lane = tid & 63;
  // bijective XCD swizzle: XCD i gets a contiguous chunk of tile-space
  int flat = blockIdx.x;
  {
    const int qq = (int)gridDim.x >> 3;
    flat = (flat & 7) * qq + (flat >> 3);
  }
  const int m0 = (flat / NBX) * TM;
  int n0 = (flat % NBX) * TN;
  if constexpr (MODE == 2) {
    if (n0 >= (N >> 1)) { B = B2; bias = bias2; D = D2; n0 -= (N >> 1); }
  }
  const int wm = (wave >> 1) * WM, wn = (wave & 1) * WN;
  const int sub = lane >> 3, col8 = (lane & 7) * 8;
  const int mlo = lane & 15, khi = lane >> 4;
  f32x4 acc[AFR][BFR] = {};

  auto stage = [&](int buf, int k0) {
#pragma unroll
    for (int r = 0; r < WCH; ++r) {
      int ci = wave * WCH + r;
      if (ci < ACH) {
        int row = ci * 8 + sub;
        int g = m0 + row;
        if (g > M - 1) g = M - 1;  // clamp partial M-tiles (KV GEMM)
        async16(A + (size_t)g * K + k0 + col8, &sA[buf][ci * 512]);
      } else {
        int cj = ci - ACH;
        int row = cj * 8 + sub;
        async16(B + (size_t)(n0 + row) * K + k0 + col8, &sB[buf][cj * 512]);
      }
    }
  };

  const int NT = K >> 6;
  // prologue: stage tiles 0 and 1; wait tile 0 (oldest 8 of 16 in flight)
  stage(0, 0);
  stage(1, 64);
  asm volatile("s_waitcnt vmcnt(8)" ::: "memory");
  __builtin_amdgcn_s_barrier();
  __builtin_amdgcn_sched_barrier(0);

  for (int t = 0; t < NT; ++t) {
    const int cur = t & 1;
#pragma unroll
    for (int kc = 0; kc < 2; ++kc) {
      bf16x8 af[AFR], bfv[BFR];
      const int ko = kc * 32 + khi * 8;
#pragma unroll
      for (int i = 0; i < AFR; ++i)
        af[i] = *(const bf16x8*)&sA[cur][(wm + i * 16 + mlo) * 64 + ko];
#pragma unroll
      for (int j = 0; j < BFR; ++j)
        bfv[j] = *(const bf16x8*)&sB[cur][(wn + j * 16 + mlo) * 64 + ko];
#pragma unroll
      for (int i = 0; i < AFR; ++i)
#pragma unroll
        for (int j = 0; j < BFR; ++j)
          acc[i][j] = __builtin_amdgcn_mfma_f32_16x16x32_bf16(af[i], bfv[j],
                                                              acc[i][j], 0, 0, 0);
    }
    // release buf[cur]: all my LDS reads retired, then block-wide barrier
    asm volatile("s_waitcnt lgkmcnt(0)" ::: "memory");
    __builtin_amdgcn_s_barrier();
    if (t + 2 < NT) {
      stage(cur, (t + 2) << 6);               // overwrite released buffer
      asm volatile("s_waitcnt vmcnt(8)" ::: "memory");  // tile t+1 landed
      __builtin_amdgcn_s_barrier();
      __builtin_amdgcn_sched_barrier(0);
    } else if (t + 1 < NT) {
      asm volatile("s_waitcnt vmcnt(0)" ::: "memory");  // last tile landed
      __builtin_amdgcn_s_barrier();
      __builtin_amdgcn_sched_barrier(0);
    }
  }

  if constexpr (MODE == 0) {
    // Q-proj epilogue: bias + posenc, bf16 round, store, partial row stats
    __shared__ float sRS[TM][2][2];
    bf16* Dq = (bf16*)D;
    const int wnh = wave & 1;
#pragma unroll
    for (int i = 0; i < AFR; ++i) {
#pragma unroll
      for (int r = 0; r < 4; ++r) {
        const int rowt = wm + i * 16 + khi * 4 + r;
        const int m = m0 + rowt;
        const int hw = m & (HWD - 1);
        const float pex = (float)(hw & 63) * (0.05f / 63.0f);
        const float pey = (float)(hw >> 6) * (0.05f / 63.0f);
        float s = 0.f, sq = 0.f;
#pragma unroll
        for (int j = 0; j < BFR; ++j) {
          const int n = n0 + wn + j * 16 + mlo;
          float v = acc[i][j][r] + bias[n] + (n < 256 ? pex : pey);
          bf16 hv = (bf16)v;
          Dq[(size_t)m * CD + n] = hv;
          float vr = (float)hv;
          s += vr;
          sq += vr * vr;
        }
        s += __shfl_xor(s, 1); sq += __shfl_xor(sq, 1);
        s += __shfl_xor(s, 2); sq += __shfl_xor(sq, 2);
        s += __shfl_xor(s, 4); sq += __shfl_xor(sq, 4);
        s += __shfl_xor(s, 8); sq += __shfl_xor(sq, 8);
        if (mlo == 0) { sRS[rowt][wnh][0] = s; sRS[rowt][wnh][1] = sq; }
      }
    }
    __syncthreads();
    if (tid < TM) {
      float s = sRS[tid][0][0] + sRS[tid][1][0];
      float sq = sRS[tid][0][1] + sRS[tid][1][1];
      float2* pst = (float2*)xres;
      pst[(size_t)(n0 >> 7) * (BD * HWD) + (m0 + tid)] = make_float2(s, sq);
    }
  } else if constexpr (MODE == 3) {
    // token-major epilogue: r=0..3 are 4 consecutive hw for one channel n
    float bn[BFR];
#pragma unroll
    for (int j = 0; j < BFR; ++j) bn[j] = bias[n0 + wn + j * 16 + mlo];
#pragma unroll
    for (int i = 0; i < AFR; ++i) {
      const int m = m0 + wm + i * 16 + khi * 4;  // token (same b for whole tile)
      const int b = m >> 12, hw = m & (HWD - 1);
      const float* xr0 = xres + ((size_t)b * CD) * HWD + hw;
      float* d0 = D + ((size_t)b * CD) * HWD + hw;
#pragma unroll
      for (int j = 0; j < BFR; ++j) {
        const size_t off = (size_t)(n0 + wn + j * 16 + mlo) * HWD;
        float4 xr = *(const float4*)(xr0 + off);
        float4 ov;
        ov.x = acc[i][j][0] + bn[j] + xr.x;
        ov.y = acc[i][j][1] + bn[j] + xr.y;
        ov.z = acc[i][j][2] + bn[j] + xr.z;
        ov.w = acc[i][j][3] + bn[j] + xr.w;
        *(float4*)(d0 + off) = ov;
      }
    }
  } else {
#pragma unroll
    for (int i = 0; i < AFR; ++i) {
      const int mb = m0 + wm + i * 16 + khi * 4;
#pragma unroll
      for (int j = 0; j < BFR; ++j) {
        const int n = n0 + wn + j * 16 + mlo;
#pragma unroll
        for (int r = 0; r < 4; ++r) {
          const int m = mb + r;
          if (m < M) D[(size_t)m * CD + n] = acc[i][j][r] + bias[n];
        }
      }
    }
  }
}

// ---------------------------------------------------------------------------
// LayerNorm over rows of 512 (wave per row) — k path only.
// khlayout=1: Y = kh [B,NH,L,HD] bf16 (head-split)
// ---------------------------------------------------------------------------
__global__ __launch_bounds__(256) void ln_rows(const float* __restrict__ X,
                                               const float* __restrict__ gg,
                                               const float* __restrict__ bb,
                                               bf16* __restrict__ Y, int nrows,
                                               int khlayout) {
  const int wv = threadIdx.x >> 6, lane = threadIdx.x & 63;
  const int row = blockIdx.x * 4 + wv;
  if (row >= nrows) return;
  const float* xr = X + (size_t)row * CD + lane * 8;
  float4 v0 = *(const float4*)xr;
  float4 v1 = *(const float4*)(xr + 4);
  float xv[8] = {v0.x, v0.y, v0.z, v0.w, v1.x, v1.y, v1.z, v1.w};
  float s = 0.f, sq = 0.f;
#pragma unroll
  for (int j = 0; j < 8; ++j) { s += xv[j]; sq += xv[j] * xv[j]; }
#pragma unroll
  for (int off = 1; off < 64; off <<= 1) {
    s += __shfl_xor(s, off);
    sq += __shfl_xor(sq, off);
  }
  float mean = s * (1.0f / 512.0f);
  float var = sq * (1.0f / 512.0f) - mean * mean;
  float rstd = rsqrtf(var + 1e-5f);
  const int c0 = lane * 8;
  union { uint4 u; unsigned short us[8]; } pk;
#pragma unroll
  for (int j = 0; j < 8; ++j)
    pk.us[j] = bfb((xv[j] - mean) * rstd * gg[c0 + j] + bb[c0 + j]);
  size_t ya;
  if (khlayout) {
    int bq = row / LD, l = row - bq * LD;
    int hh = lane >> 3, dd = (lane & 7) * 8;
    ya = (((size_t)(bq * NH_ + hh)) * LD + l) * HD_ + dd;
  } else {
    ya = (size_t)row * CD + c0;
  }
  *(uint4*)(Y + ya) = pk.u;
}

// ---------------------------------------------------------------------------
// vraw [B*L, 512] fp32 -> vt [B*NH, HD, 96] bf16 (key dim transposed,
// cols 77..95 zero so PV K-loop can run over 96 with no masking)
// ---------------------------------------------------------------------------
__global__ __launch_bounds__(256) void make_vt(const float* __restrict__ vraw,
                                               bf16* __restrict__ vt) {
  const int bh = blockIdx.x, b = bh >> 3, h = bh & 7;
  const int tid = threadIdx.x, d = tid & 63, lg = tid >> 6;
  for (int l = lg; l < 96; l += 4) {
    float v = 0.f;
    if (l < LD) v = vraw[((size_t)(b * LD + l)) * CD + h * HD_ + d];
    vt[((size_t)(bh * HD_ + d)) * 96 + l] = (bf16)v;
  }
}

// ---------------------------------------------------------------------------
// Attention: block = (64 queries, head h, batch b); 4 waves x 16-query strips.
// Q arrives pre-LN (bf16, bias+pe included); LN applied in-register here
// using per-row partial stats from the Q-GEMM (pstat: 4 x float2 per row).
// ---------------------------------------------------------------------------
__global__ __launch_bounds__(256) void attn_k(const bf16* __restrict__ Q,
                                              const float2* __restrict__ PST,
                                              const float* __restrict__ G1,
                                              const float* __restrict__ B1,
                                              const bf16* __restrict__ KH,
                                              const bf16* __restrict__ VT,
                                              bf16* __restrict__ O) {
  __shared__ bf16 P[4][16 * 104];  // per-wave 16x96 P, stride 104 vs bank conflicts
  const int tid = threadIdx.x, wv = tid >> 6, lane = tid & 63;
  const int m = lane & 15, kg = lane >> 4;
  const int q0 = blockIdx.x * 64, h = blockIdx.y, b = blockIdx.z;
  const int bh = b * NH_ + h;

  // raw (pre-LN) Q fragments
  const int rowg = b * HWD + q0 + wv * 16 + m;
  const size_t qoff = (size_t)rowg * CD + h * HD_;
  bf16x8 a0r = *(const bf16x8*)(Q + qoff + kg * 8);
  bf16x8 a1r = *(const bf16x8*)(Q + qoff + 32 + kg * 8);

  // combine the 4 per-nblock partial stats (one per kg lane-group)
  float2 st = PST[(size_t)kg * (BD * HWD) + rowg];
  float s = st.x, sq = st.y;
  s += __shfl_xor(s, 16); sq += __shfl_xor(sq, 16);
  s += __shfl_xor(s, 32); sq += __shfl_xor(sq, 32);
  const float mean = s * (1.0f / 512.0f);
  const float var = sq * (1.0f / 512.0f) - mean * mean;
  const float rstd = rsqrtf(var + 1e-5f);

  // per-lane LN params for channels c0..c0+7 and c0+32..c0+39
  const int c0 = h * HD_ + kg * 8;
  float4 ga = *(const float4*)(G1 + c0), gb = *(const float4*)(G1 + c0 + 4);
  float4 gc = *(const float4*)(G1 + c0 + 32), gd = *(const float4*)(G1 + c0 + 36);
  float4 ta = *(const float4*)(B1 + c0), tb = *(const float4*)(B1 + c0 + 4);
  float4 tc = *(const float4*)(B1 + c0 + 32), td = *(const float4*)(B1 + c0 + 36);
  const float gg[16] = {ga.x, ga.y, ga.z, ga.w, gb.x, gb.y, gb.z, gb.w,
                        gc.x, gc.y, gc.z, gc.w, gd.x, gd.y, gd.z, gd.w};
  const float bbv[16] = {ta.x, ta.y, ta.z, ta.w, tb.x, tb.y, tb.z, tb.w,
                         tc.x, tc.y, tc.z, tc.w, td.x, td.y, td.z, td.w};
  bf16x8 a0, a1;
#pragma unroll
  for (int e = 0; e < 8; ++e) {
    a0[e] = (bf16)(((float)a0r[e] - mean) * rstd * gg[e] + bbv[e]);
    a1[e] = (bf16)(((float)a1r[e] - mean) * rstd * gg[8 + e] + bbv[8 + e]);
  }

  // S = Q K^T : 5 key tiles of 16
  const bf16* Kb = KH + (size_t)bh * LD * HD_;
  f32x4 sacc[5];
#pragma unroll
  for (int kt = 0; kt < 5; ++kt) {
    int key = kt * 16 + m;
    if (key > LD - 1) key = LD - 1;  // clamped rows get masked below
    const bf16* kr = Kb + key * HD_ + kg * 8;
    bf16x8 b0 = *(const bf16x8*)kr;
    bf16x8 b1 = *(const bf16x8*)(kr + 32);
    f32x4 z = {0.f, 0.f, 0.f, 0.f};
    z = __builtin_amdgcn_mfma_f32_16x16x32_bf16(a0, b0, z, 0, 0, 0);
    z = __builtin_amdgcn_mfma_f32_16x16x32_bf16(a1, b1, z, 0, 0, 0);
    sacc[kt] = z;
  }

  // softmax per row (row = kg*4+r, cols live in lanes kg*16..kg*16+15)
  bf16* Pw = &P[wv][0];
#pragma unroll
  for (int r = 0; r < 4; ++r) {
    float sc[5];
#pragma unroll
    for (int kt = 0; kt < 5; ++kt) {
      float v = sacc[kt][r] * 0.125f;  // HD^-0.5
      if (kt == 4 && m >= LD - 64) v = -3.0e38f;
      sc[kt] = v;
    }
    float mx = fmaxf(fmaxf(fmaxf(sc[0], sc[1]), fmaxf(sc[2], sc[3])), sc[4]);
    mx = fmaxf(mx, __shfl_xor(mx, 1));
    mx = fmaxf(mx, __shfl_xor(mx, 2));
    mx = fmaxf(mx, __shfl_xor(mx, 4));
    mx = fmaxf(mx, __shfl_xor(mx, 8));
    float sum = 0.f;
#pragma unroll
    for (int kt = 0; kt < 5; ++kt) {
      sc[kt] = __expf(sc[kt] - mx);
      sum += sc[kt];
    }
    sum += __shfl_xor(sum, 1);
    sum += __shfl_xor(sum, 2);
    sum += __shfl_xor(sum, 4);
    sum += __shfl_xor(sum, 8);
    float inv = 1.0f / sum;
    const int prow = kg * 4 + r;
#pragma unroll
    for (int kt = 0; kt < 5; ++kt)
      Pw[prow * 104 + kt * 16 + m] = (bf16)(sc[kt] * inv);
    Pw[prow * 104 + 80 + m] = (bf16)0.f;  // zero pad cols 80..95
  }
  __syncthreads();

  // O = P V : A-frags from LDS P, B-frags from global vt (L2-resident)
  bf16x8 ap[3];
#pragma unroll
  for (int kc = 0; kc < 3; ++kc)
    ap[kc] = *(const bf16x8*)&Pw[m * 104 + kc * 32 + kg * 8];

  const bf16* Vb = VT + (size_t)bh * HD_ * 96;
  f32x4 o[4] = {};
#pragma unroll
  for (int nt = 0; nt < 4; ++nt) {
#pragma unroll
    for (int kc = 0; kc < 3; ++kc) {
      bf16x8 bv = *(const bf16x8*)(Vb + (nt * 16 + m) * 96 + kc * 32 + kg * 8);
      o[nt] = __builtin_amdgcn_mfma_f32_16x16x32_bf16(ap[kc], bv, o[nt], 0, 0, 0);
    }
  }
#pragma unroll
  for (int nt = 0; nt < 4; ++nt)
#pragma unroll
    for (int r = 0; r < 4; ++r) {
      const int row = b * HWD + q0 + wv * 16 + kg * 4 + r;
      O[(size_t)row * CD + h * HD_ + nt * 16 + m] = (bf16)(o[nt][r]);
    }
}

// ---------------------------------------------------------------------------
extern "C" void kernel_launch(void* const* d_in, const int* in_sizes, int n_in,
                              void* d_out, int out_size, void* d_ws, size_t ws_size,
                              hipStream_t stream) {
  const float* x    = (const float*)d_in[0];
  const float* text = (const float*)d_in[1];
  const float* wq   = (const float*)d_in[2];
  const float* bq   = (const float*)d_in[3];
  const float* wk   = (const float*)d_in[4];
  const float* bk   = (const float*)d_in[5];
  const float* wv   = (const float*)d_in[6];
  const float* bv   = (const float*)d_in[7];
  const float* wo   = (const float*)d_in[8];
  const float* bo   = (const float*)d_in[9];
  const float* g1   = (const float*)d_in[10];
  const float* b1   = (const float*)d_in[11];
  const float* g2   = (const float*)d_in[12];
  const float* b2   = (const float*)d_in[13];
  float* out = (float*)d_out;

  char* p = (char*)d_ws;
  auto alloc = [&](size_t bytes) {
    char* r = p;
    p += (bytes + 255) & ~(size_t)255;
    return r;
  };
  bf16* xt     = (bf16*)alloc((size_t)BD * HWD * CD * 2);
  bf16* attn_o = (bf16*)alloc((size_t)BD * HWD * CD * 2);
  bf16* textb  = (bf16*)alloc((size_t)BD * LD * DD * 2);
  bf16* wqb    = (bf16*)alloc((size_t)CD * CD * 2);
  bf16* wkb    = (bf16*)alloc((size_t)CD * DD * 2);
  bf16* wvb    = (bf16*)alloc((size_t)CD * DD * 2);
  bf16* wob    = (bf16*)alloc((size_t)CD * CD * 2);
  float* kraw  = (float*)alloc((size_t)BD * LD * CD * 4);
  float* vraw  = (float*)alloc((size_t)BD * LD * CD * 4);
  bf16* kh     = (bf16*)alloc((size_t)BD * NH_ * LD * HD_ * 2);
  bf16* vt     = (bf16*)alloc((size_t)BD * NH_ * HD_ * 96 * 2);
  float* pstat = (float*)alloc((size_t)4 * BD * HWD * 2 * 4);  // 4 nblk x row x {s,sq}
  // d_out doubles as bf16 pre-LN q scratch until the final O-proj GEMM
  bf16* qbf = (bf16*)out;

  // 0: convert inputs
  xpose_cvt<<<dim3(HWD / 64, CD / 64, BD), 256, 0, stream>>>(x, xt);
  cvt_all<<<1102, 256, 0, stream>>>(text, wq, wk, wv, wo,
                                    textb, wqb, wkb, wvb, wob);

  // 1: fused K+V projection (logical N=1024), LN(k), V transpose
  gemm_bt<128, 128, 2, 8><<<80, 256, 0, stream>>>(
      textb, wkb, BD * LD, 2 * CD, DD, bk, nullptr, kraw, wvb, bv, vraw);
  ln_rows<<<(BD * LD + 3) / 4, 256, 0, stream>>>(kraw, g2, b2, kh, BD * LD, 1);
  make_vt<<<BD * NH_, 256, 0, stream>>>(vraw, vt);

  // 2: Q projection (+bias+posenc), bf16 out + partial row stats (LN in attn)
  gemm_bt<128, 128, 0, 4><<<2048, 256, 0, stream>>>(
      xt, wqb, BD * HWD, CD, CD, bq, pstat, (float*)qbf,
      nullptr, nullptr, nullptr);

  // 3: attention (applies LN(q) in-register from pstat)
  attn_k<<<dim3(HWD / 64, NH_, BD), 256, 0, stream>>>(
      qbf, (const float2*)pstat, g1, b1, kh, vt, attn_o);

  // 4: output projection, token-major (+bias +residual), float4 epilogue
  gemm_bt<128, 128, 3, 4><<<2048, 256, 0, stream>>>(
      attn_o, wob, BD * HWD, CD, CD, bo, x, out, nullptr, nullptr, nullptr);
}

// Round 5
// 524.618 us; speedup vs baseline: 1.1985x; 1.0284x over previous
//
#include <hip/hip_runtime.h>
#include <stdint.h>

// Problem constants
#define BD   16
#define CD   512
#define HD_  64
#define NH_  8
#define HWD  4096
#define LD   77
#define DD   768

typedef __bf16 bf16;
typedef bf16 bf16x8 __attribute__((ext_vector_type(8)));
typedef float f32x4 __attribute__((ext_vector_type(4)));

__device__ __forceinline__ void async16(const bf16* g, bf16* l) {
  __builtin_amdgcn_global_load_lds(
      (const __attribute__((address_space(1))) void*)g,
      (__attribute__((address_space(3))) void*)l, 16, 0, 0);
}

__device__ __forceinline__ unsigned short bfb(float f) {
  bf16 h = (bf16)f;
  return __builtin_bit_cast(unsigned short, h);
}

// ---------------------------------------------------------------------------
// K0a: transpose+convert x [B,C,HW] f32 -> xt [B*HW, C] bf16 (LDS tile xpose)
// ---------------------------------------------------------------------------
__global__ __launch_bounds__(256) void xpose_cvt(const float* __restrict__ X,
                                                 bf16* __restrict__ Y) {
  __shared__ float tile[64][68];
  const int b = blockIdx.z, c0 = blockIdx.y * 64, t0 = blockIdx.x * 64;
  const int tid = threadIdx.x;
  const float* Xb = X + ((size_t)b * CD + c0) * HWD + t0;
#pragma unroll
  for (int p = 0; p < 4; ++p) {
    int c = (tid >> 4) + p * 16;
    int t = (tid & 15) * 4;
    float4 v = *(const float4*)(Xb + (size_t)c * HWD + t);
    *(float4*)&tile[c][t] = v;
  }
  __syncthreads();
  int t = tid >> 2, cb = (tid & 3) * 16;
  union { uint4 u[2]; unsigned short us[16]; } pk;
#pragma unroll
  for (int j = 0; j < 16; ++j) pk.us[j] = bfb(tile[cb + j][t]);
  uint4* Yp = (uint4*)(Y + ((size_t)(b * HWD + t0 + t)) * CD + c0 + cb);
  Yp[0] = pk.u[0];
  Yp[1] = pk.u[1];
}

// ---------------------------------------------------------------------------
// K0b: all five f32 -> bf16 converts in ONE dispatch
// ---------------------------------------------------------------------------
__global__ __launch_bounds__(256) void cvt_all(
    const float* __restrict__ t, const float* __restrict__ q,
    const float* __restrict__ k, const float* __restrict__ v,
    const float* __restrict__ o, bf16* __restrict__ tb, bf16* __restrict__ qb,
    bf16* __restrict__ kb, bf16* __restrict__ vb, bf16* __restrict__ ob) {
  // blocks per segment: text 462, wq 128, wk 192, wv 192, wo 128
  int bid = blockIdx.x;
  const float* src;
  bf16* dst;
  if (bid < 462) { src = t; dst = tb; }
  else if (bid < 590) { src = q; dst = qb; bid -= 462; }
  else if (bid < 782) { src = k; dst = kb; bid -= 590; }
  else if (bid < 974) { src = v; dst = vb; bid -= 782; }
  else { src = o; dst = ob; bid -= 974; }
  int i = (bid * 256 + threadIdx.x) * 8;
  float4 a = *(const float4*)(src + i);
  float4 c = *(const float4*)(src + i + 4);
  union { uint4 u; unsigned short us[8]; } pk;
  pk.us[0] = bfb(a.x); pk.us[1] = bfb(a.y); pk.us[2] = bfb(a.z); pk.us[3] = bfb(a.w);
  pk.us[4] = bfb(c.x); pk.us[5] = bfb(c.y); pk.us[6] = bfb(c.z); pk.us[7] = bfb(c.w);
  *(uint4*)(dst + i) = pk.u;
}

// ---------------------------------------------------------------------------
// m97-style GEMM + counted-vmcnt double-buffer prefetch + T2 LDS XOR-swizzle.
// Swizzle (rule #21, both-sides): global_load_lds writes linearly, so the
// SOURCE column is pre-swizzled (col8 ^ sub*8) and the ds_read_b128 address
// applies the same XOR (ko ^ (row&7)*8) -> 16-way bank conflict becomes
// 2-way (free). Stage addressing is hoisted: per-(wave,r) pointers computed
// once, stage() only adds t*64.
// D[M,N] = A[M,K] * B[N,K]^T, flat 1D grid, bijective XCD swizzle.
// MODE 0: Q-proj. Epilogue: += bq[n] + 0.05*pe; round bf16 -> Dq; partial
//         row stats -> pstat[(n0/128)*65536 + m]. LN applied in attn_k.
// MODE 2: fused K/V proj (logical N=1024). K side -> kraw fp32. V side
//         writes vt [B*NH, HD, 96] bf16 directly (vt pre-zeroed).
// MODE 3: O-proj, token-major; float4 epilogue += bo[n] + x residual.
// ---------------------------------------------------------------------------
template <int TM, int TN, int MODE, int NBX>
__global__ __launch_bounds__(256)
void gemm_bt(const bf16* __restrict__ A, const bf16* __restrict__ B,
             int M, int N, int K,
             const float* __restrict__ bias, const float* __restrict__ xres,
             float* __restrict__ D,
             const bf16* __restrict__ B2, const float* __restrict__ bias2,
             float* __restrict__ D2) {
  constexpr int WM = TM / 2, WN = TN / 2;
  constexpr int AFR = WM / 16, BFR = WN / 16;
  constexpr int ACH = TM / 8, TCH = (TM + TN) / 8, WCH = TCH / 4;
  static_assert(WCH == 8, "vmcnt(8) literal assumes 8 loads/wave/tile");
  __shared__ bf16 sM[2][(TM + TN) * 64];
  const int tid = threadIdx.x, wave = tid >> 6, lane = tid & 63;
  // bijective XCD swizzle: XCD i gets a contiguous chunk of tile-space
  int flat = blockIdx.x;
  {
    const int qq = (int)gridDim.x >> 3;
    flat = (flat & 7) * qq + (flat >> 3);
  }
  const int m0 = (flat / NBX) * TM;
  int n0 = (flat % NBX) * TN;
  bool vside = false;
  if constexpr (MODE == 2) {
    if (n0 >= (N >> 1)) { B = B2; bias = bias2; vside = true; n0 -= (N >> 1); }
  }
  const int wm = (wave >> 1) * WM, wn = (wave & 1) * WN;
  const int sub = lane >> 3, col8 = (lane & 7) * 8;
  const int csw = col8 ^ (sub * 8);  // pre-swizzled source column
  const int mlo = lane & 15, khi = lane >> 4;
  const int rxor = (mlo & 7) * 8;    // read-side swizzle XOR
  f32x4 acc[AFR][BFR] = {};

  // hoisted per-(wave,r) staging pointers / LDS offsets
  const bf16* gp[WCH];
  int ldoff[WCH];
#pragma unroll
  for (int r = 0; r < WCH; ++r) {
    int ci = wave * WCH + r;
    if (ci < ACH) {
      int g = m0 + ci * 8 + sub;
      if (g > M - 1) g = M - 1;  // clamp partial M-tiles (KV GEMM)
      gp[r] = A + (size_t)g * K + csw;
      ldoff[r] = ci * 512;
    } else {
      int cj = ci - ACH;
      gp[r] = B + (size_t)(n0 + cj * 8 + sub) * K + csw;
      ldoff[r] = TM * 64 + cj * 512;
    }
  }

  auto stage = [&](int buf, int t) {
    const int k0 = t << 6;
#pragma unroll
    for (int r = 0; r < WCH; ++r)
      async16(gp[r] + k0, &sM[buf][ldoff[r]]);
  };

  const int NT = K >> 6;
  // prologue: stage tiles 0 and 1; wait tile 0 (oldest 8 of 16 in flight)
  stage(0, 0);
  stage(1, 1);
  asm volatile("s_waitcnt vmcnt(8)" ::: "memory");
  __builtin_amdgcn_s_barrier();
  __builtin_amdgcn_sched_barrier(0);

  for (int t = 0; t < NT; ++t) {
    const int cur = t & 1;
    const bf16* sA = &sM[cur][0];
    const bf16* sB = &sM[cur][TM * 64];
#pragma unroll
    for (int kc = 0; kc < 2; ++kc) {
      bf16x8 af[AFR], bfv[BFR];
      const int ko = kc * 32 + khi * 8;
      const int kos = ko ^ rxor;  // swizzled column (rows rA&7 == mlo&7)
#pragma unroll
      for (int i = 0; i < AFR; ++i)
        af[i] = *(const bf16x8*)&sA[(wm + i * 16 + mlo) * 64 + kos];
#pragma unroll
      for (int j = 0; j < BFR; ++j)
        bfv[j] = *(const bf16x8*)&sB[(wn + j * 16 + mlo) * 64 + kos];
      __builtin_amdgcn_s_setprio(1);
#pragma unroll
      for (int i = 0; i < AFR; ++i)
#pragma unroll
        for (int j = 0; j < BFR; ++j)
          acc[i][j] = __builtin_amdgcn_mfma_f32_16x16x32_bf16(af[i], bfv[j],
                                                              acc[i][j], 0, 0, 0);
      __builtin_amdgcn_s_setprio(0);
    }
    // release buf[cur]: all my LDS reads retired, then block-wide barrier
    asm volatile("s_waitcnt lgkmcnt(0)" ::: "memory");
    __builtin_amdgcn_s_barrier();
    if (t + 2 < NT) {
      stage(cur, t + 2);                      // overwrite released buffer
      asm volatile("s_waitcnt vmcnt(8)" ::: "memory");  // tile t+1 landed
      __builtin_amdgcn_s_barrier();
      __builtin_amdgcn_sched_barrier(0);
    } else if (t + 1 < NT) {
      asm volatile("s_waitcnt vmcnt(0)" ::: "memory");  // last tile landed
      __builtin_amdgcn_s_barrier();
      __builtin_amdgcn_sched_barrier(0);
    }
  }

  if constexpr (MODE == 0) {
    // Q-proj epilogue: bias + posenc, bf16 round, store, partial row stats
    __shared__ float sRS[TM][2][2];
    bf16* Dq = (bf16*)D;
    const int wnh = wave & 1;
#pragma unroll
    for (int i = 0; i < AFR; ++i) {
#pragma unroll
      for (int r = 0; r < 4; ++r) {
        const int rowt = wm + i * 16 + khi * 4 + r;
        const int m = m0 + rowt;
        const int hw = m & (HWD - 1);
        const float pex = (float)(hw & 63) * (0.05f / 63.0f);
        const float pey = (float)(hw >> 6) * (0.05f / 63.0f);
        float s = 0.f, sq = 0.f;
#pragma unroll
        for (int j = 0; j < BFR; ++j) {
          const int n = n0 + wn + j * 16 + mlo;
          float v = acc[i][j][r] + bias[n] + (n < 256 ? pex : pey);
          bf16 hv = (bf16)v;
          Dq[(size_t)m * CD + n] = hv;
          float vr = (float)hv;
          s += vr;
          sq += vr * vr;
        }
        s += __shfl_xor(s, 1); sq += __shfl_xor(sq, 1);
        s += __shfl_xor(s, 2); sq += __shfl_xor(sq, 2);
        s += __shfl_xor(s, 4); sq += __shfl_xor(sq, 4);
        s += __shfl_xor(s, 8); sq += __shfl_xor(sq, 8);
        if (mlo == 0) { sRS[rowt][wnh][0] = s; sRS[rowt][wnh][1] = sq; }
      }
    }
    __syncthreads();
    if (tid < TM) {
      float s = sRS[tid][0][0] + sRS[tid][1][0];
      float sq = sRS[tid][0][1] + sRS[tid][1][1];
      float2* pst = (float2*)xres;
      pst[(size_t)(n0 >> 7) * (BD * HWD) + (m0 + tid)] = make_float2(s, sq);
    }
  } else if constexpr (MODE == 3) {
    // token-major epilogue: r=0..3 are 4 consecutive hw for one channel n
    float bn[BFR];
#pragma unroll
    for (int j = 0; j < BFR; ++j) bn[j] = bias[n0 + wn + j * 16 + mlo];
#pragma unroll
    for (int i = 0; i < AFR; ++i) {
      const int m = m0 + wm + i * 16 + khi * 4;  // token (same b for whole tile)
      const int b = m >> 12, hw = m & (HWD - 1);
      const float* xr0 = xres + ((size_t)b * CD) * HWD + hw;
      float* d0 = D + ((size_t)b * CD) * HWD + hw;
#pragma unroll
      for (int j = 0; j < BFR; ++j) {
        const size_t off = (size_t)(n0 + wn + j * 16 + mlo) * HWD;
        float4 xr = *(const float4*)(xr0 + off);
        float4 ov;
        ov.x = acc[i][j][0] + bn[j] + xr.x;
        ov.y = acc[i][j][1] + bn[j] + xr.y;
        ov.z = acc[i][j][2] + bn[j] + xr.z;
        ov.w = acc[i][j][3] + bn[j] + xr.w;
        *(float4*)(d0 + off) = ov;
      }
    }
  } else {
    // MODE 2: K side -> kraw fp32 rows; V side -> vt bf16 directly
    bf16* vt = (bf16*)D2;
#pragma unroll
    for (int i = 0; i < AFR; ++i) {
      const int mb = m0 + wm + i * 16 + khi * 4;
#pragma unroll
      for (int j = 0; j < BFR; ++j) {
        const int n = n0 + wn + j * 16 + mlo;
#pragma unroll
        for (int r = 0; r < 4; ++r) {
          const int m = mb + r;
          if (m < M) {
            float v = acc[i][j][r] + bias[n];
            if (!vside) {
              D[(size_t)m * CD + n] = v;
            } else {
              const int b = m / LD, l = m - b * LD;
              const int h = n >> 6, d = n & 63;
              vt[(((size_t)(b * NH_ + h)) * HD_ + d) * 96 + l] = (bf16)v;
            }
          }
        }
      }
    }
  }
}

// ---------------------------------------------------------------------------
// LayerNorm over rows of 512 (wave per row) — k path only.
// Y = kh [B,NH,L,HD] bf16 (head-split)
// ---------------------------------------------------------------------------
__global__ __launch_bounds__(256) void ln_rows(const float* __restrict__ X,
                                               const float* __restrict__ gg,
                                               const float* __restrict__ bb,
                                               bf16* __restrict__ Y, int nrows) {
  const int wv = threadIdx.x >> 6, lane = threadIdx.x & 63;
  const int row = blockIdx.x * 4 + wv;
  if (row >= nrows) return;
  const float* xr = X + (size_t)row * CD + lane * 8;
  float4 v0 = *(const float4*)xr;
  float4 v1 = *(const float4*)(xr + 4);
  float xv[8] = {v0.x, v0.y, v0.z, v0.w, v1.x, v1.y, v1.z, v1.w};
  float s = 0.f, sq = 0.f;
#pragma unroll
  for (int j = 0; j < 8; ++j) { s += xv[j]; sq += xv[j] * xv[j]; }
#pragma unroll
  for (int off = 1; off < 64; off <<= 1) {
    s += __shfl_xor(s, off);
    sq += __shfl_xor(sq, off);
  }
  float mean = s * (1.0f / 512.0f);
  float var = sq * (1.0f / 512.0f) - mean * mean;
  float rstd = rsqrtf(var + 1e-5f);
  const int c0 = lane * 8;
  union { uint4 u; unsigned short us[8]; } pk;
#pragma unroll
  for (int j = 0; j < 8; ++j)
    pk.us[j] = bfb((xv[j] - mean) * rstd * gg[c0 + j] + bb[c0 + j]);
  int bq = row / LD, l = row - bq * LD;
  int hh = lane >> 3, dd = (lane & 7) * 8;
  size_t ya = (((size_t)(bq * NH_ + hh)) * LD + l) * HD_ + dd;
  *(uint4*)(Y + ya) = pk.u;
}

// ---------------------------------------------------------------------------
// Attention: block = (64 queries, head h, batch b); 4 waves x 16-query strips.
// Q arrives pre-LN (bf16, bias+pe included); LN applied in-register here
// using per-row partial stats from the Q-GEMM (pstat: 4 x float2 per row).
// ---------------------------------------------------------------------------
__global__ __launch_bounds__(256) void attn_k(const bf16* __restrict__ Q,
                                              const float2* __restrict__ PST,
                                              const float* __restrict__ G1,
                                              const float* __restrict__ B1,
                                              const bf16* __restrict__ KH,
                                              const bf16* __restrict__ VT,
                                              bf16* __restrict__ O) {
  __shared__ bf16 P[4][16 * 104];  // per-wave 16x96 P, stride 104 vs bank conflicts
  const int tid = threadIdx.x, wv = tid >> 6, lane = tid & 63;
  const int m = lane & 15, kg = lane >> 4;
  const int q0 = blockIdx.x * 64, h = blockIdx.y, b = blockIdx.z;
  const int bh = b * NH_ + h;

  // raw (pre-LN) Q fragments
  const int rowg = b * HWD + q0 + wv * 16 + m;
  const size_t qoff = (size_t)rowg * CD + h * HD_;
  bf16x8 a0r = *(const bf16x8*)(Q + qoff + kg * 8);
  bf16x8 a1r = *(const bf16x8*)(Q + qoff + 32 + kg * 8);

  // combine the 4 per-nblock partial stats (one per kg lane-group)
  float2 st = PST[(size_t)kg * (BD * HWD) + rowg];
  float s = st.x, sq = st.y;
  s += __shfl_xor(s, 16); sq += __shfl_xor(sq, 16);
  s += __shfl_xor(s, 32); sq += __shfl_xor(sq, 32);
  const float mean = s * (1.0f / 512.0f);
  const float var = sq * (1.0f / 512.0f) - mean * mean;
  const float rstd = rsqrtf(var + 1e-5f);

  // per-lane LN params for channels c0..c0+7 and c0+32..c0+39
  const int c0 = h * HD_ + kg * 8;
  float4 ga = *(const float4*)(G1 + c0), gb = *(const float4*)(G1 + c0 + 4);
  float4 gc = *(const float4*)(G1 + c0 + 32), gd = *(const float4*)(G1 + c0 + 36);
  float4 ta = *(const float4*)(B1 + c0), tb = *(const float4*)(B1 + c0 + 4);
  float4 tc = *(const float4*)(B1 + c0 + 32), td = *(const float4*)(B1 + c0 + 36);
  const float gg[16] = {ga.x, ga.y, ga.z, ga.w, gb.x, gb.y, gb.z, gb.w,
                        gc.x, gc.y, gc.z, gc.w, gd.x, gd.y, gd.z, gd.w};
  const float bbv[16] = {ta.x, ta.y, ta.z, ta.w, tb.x, tb.y, tb.z, tb.w,
                         tc.x, tc.y, tc.z, tc.w, td.x, td.y, td.z, td.w};
  bf16x8 a0, a1;
#pragma unroll
  for (int e = 0; e < 8; ++e) {
    a0[e] = (bf16)(((float)a0r[e] - mean) * rstd * gg[e] + bbv[e]);
    a1[e] = (bf16)(((float)a1r[e] - mean) * rstd * gg[8 + e] + bbv[8 + e]);
  }

  // S = Q K^T : 5 key tiles of 16
  const bf16* Kb = KH + (size_t)bh * LD * HD_;
  f32x4 sacc[5];
#pragma unroll
  for (int kt = 0; kt < 5; ++kt) {
    int key = kt * 16 + m;
    if (key > LD - 1) key = LD - 1;  // clamped rows get masked below
    const bf16* kr = Kb + key * HD_ + kg * 8;
    bf16x8 b0 = *(const bf16x8*)kr;
    bf16x8 b1 = *(const bf16x8*)(kr + 32);
    f32x4 z = {0.f, 0.f, 0.f, 0.f};
    z = __builtin_amdgcn_mfma_f32_16x16x32_bf16(a0, b0, z, 0, 0, 0);
    z = __builtin_amdgcn_mfma_f32_16x16x32_bf16(a1, b1, z, 0, 0, 0);
    sacc[kt] = z;
  }

  // softmax per row (row = kg*4+r, cols live in lanes kg*16..kg*16+15)
  bf16* Pw = &P[wv][0];
#pragma unroll
  for (int r = 0; r < 4; ++r) {
    float sc[5];
#pragma unroll
    for (int kt = 0; kt < 5; ++kt) {
      float v = sacc[kt][r] * 0.125f;  // HD^-0.5
      if (kt == 4 && m >= LD - 64) v = -3.0e38f;
      sc[kt] = v;
    }
    float mx = fmaxf(fmaxf(fmaxf(sc[0], sc[1]), fmaxf(sc[2], sc[3])), sc[4]);
    mx = fmaxf(mx, __shfl_xor(mx, 1));
    mx = fmaxf(mx, __shfl_xor(mx, 2));
    mx = fmaxf(mx, __shfl_xor(mx, 4));
    mx = fmaxf(mx, __shfl_xor(mx, 8));
    float sum = 0.f;
#pragma unroll
    for (int kt = 0; kt < 5; ++kt) {
      sc[kt] = __expf(sc[kt] - mx);
      sum += sc[kt];
    }
    sum += __shfl_xor(sum, 1);
    sum += __shfl_xor(sum, 2);
    sum += __shfl_xor(sum, 4);
    sum += __shfl_xor(sum, 8);
    float inv = 1.0f / sum;
    const int prow = kg * 4 + r;
#pragma unroll
    for (int kt = 0; kt < 5; ++kt)
      Pw[prow * 104 + kt * 16 + m] = (bf16)(sc[kt] * inv);
    Pw[prow * 104 + 80 + m] = (bf16)0.f;  // zero pad cols 80..95
  }
  __syncthreads();

  // O = P V : A-frags from LDS P, B-frags from global vt (L2-resident)
  bf16x8 ap[3];
#pragma unroll
  for (int kc = 0; kc < 3; ++kc)
    ap[kc] = *(const bf16x8*)&Pw[m * 104 + kc * 32 + kg * 8];

  const bf16* Vb = VT + (size_t)bh * HD_ * 96;
  f32x4 o[4] = {};
#pragma unroll
  for (int nt = 0; nt < 4; ++nt) {
#pragma unroll
    for (int kc = 0; kc < 3; ++kc) {
      bf16x8 bv = *(const bf16x8*)(Vb + (nt * 16 + m) * 96 + kc * 32 + kg * 8);
      o[nt] = __builtin_amdgcn_mfma_f32_16x16x32_bf16(ap[kc], bv, o[nt], 0, 0, 0);
    }
  }
#pragma unroll
  for (int nt = 0; nt < 4; ++nt)
#pragma unroll
    for (int r = 0; r < 4; ++r) {
      const int row = b * HWD + q0 + wv * 16 + kg * 4 + r;
      O[(size_t)row * CD + h * HD_ + nt * 16 + m] = (bf16)(o[nt][r]);
    }
}

// ---------------------------------------------------------------------------
extern "C" void kernel_launch(void* const* d_in, const int* in_sizes, int n_in,
                              void* d_out, int out_size, void* d_ws, size_t ws_size,
                              hipStream_t stream) {
  const float* x    = (const float*)d_in[0];
  const float* text = (const float*)d_in[1];
  const float* wq   = (const float*)d_in[2];
  const float* bq   = (const float*)d_in[3];
  const float* wk   = (const float*)d_in[4];
  const float* bk   = (const float*)d_in[5];
  const float* wv   = (const float*)d_in[6];
  const float* bv   = (const float*)d_in[7];
  const float* wo   = (const float*)d_in[8];
  const float* bo   = (const float*)d_in[9];
  const float* g1   = (const float*)d_in[10];
  const float* b1   = (const float*)d_in[11];
  const float* g2   = (const float*)d_in[12];
  const float* b2   = (const float*)d_in[13];
  float* out = (float*)d_out;

  char* p = (char*)d_ws;
  auto alloc = [&](size_t bytes) {
    char* r = p;
    p += (bytes + 255) & ~(size_t)255;
    return r;
  };
  bf16* xt     = (bf16*)alloc((size_t)BD * HWD * CD * 2);
  bf16* attn_o = (bf16*)alloc((size_t)BD * HWD * CD * 2);
  bf16* textb  = (bf16*)alloc((size_t)BD * LD * DD * 2);
  bf16* wqb    = (bf16*)alloc((size_t)CD * CD * 2);
  bf16* wkb    = (bf16*)alloc((size_t)CD * DD * 2);
  bf16* wvb    = (bf16*)alloc((size_t)CD * DD * 2);
  bf16* wob    = (bf16*)alloc((size_t)CD * CD * 2);
  float* kraw  = (float*)alloc((size_t)BD * LD * CD * 4);
  bf16* kh     = (bf16*)alloc((size_t)BD * NH_ * LD * HD_ * 2);
  bf16* vt     = (bf16*)alloc((size_t)BD * NH_ * HD_ * 96 * 2);
  float* pstat = (float*)alloc((size_t)4 * BD * HWD * 2 * 4);  // 4 nblk x row x {s,sq}
  // d_out doubles as bf16 pre-LN q scratch until the final O-proj GEMM
  bf16* qbf = (bf16*)out;

  // 0: convert inputs; pre-zero vt (pad cols 77..95 must be 0)
  hipMemsetAsync(vt, 0, (size_t)BD * NH_ * HD_ * 96 * 2, stream);
  xpose_cvt<<<dim3(HWD / 64, CD / 64, BD), 256, 0, stream>>>(x, xt);
  cvt_all<<<1102, 256, 0, stream>>>(text, wq, wk, wv, wo,
                                    textb, wqb, wkb, wvb, wob);

  // 1: fused K+V projection (logical N=1024); V written to vt in epilogue
  gemm_bt<128, 128, 2, 8><<<80, 256, 0, stream>>>(
      textb, wkb, BD * LD, 2 * CD, DD, bk, nullptr, kraw, wvb, bv, (float*)vt);
  ln_rows<<<(BD * LD + 3) / 4, 256, 0, stream>>>(kraw, g2, b2, kh, BD * LD);

  // 2: Q projection (+bias+posenc), bf16 out + partial row stats (LN in attn)
  gemm_bt<128, 128, 0, 4><<<2048, 256, 0, stream>>>(
      xt, wqb, BD * HWD, CD, CD, bq, pstat, (float*)qbf,
      nullptr, nullptr, nullptr);

  // 3: attention (applies LN(q) in-register from pstat)
  attn_k<<<dim3(HWD / 64, NH_, BD), 256, 0, stream>>>(
      qbf, (const float2*)pstat, g1, b1, kh, vt, attn_o);

  // 4: output projection, token-major (+bias +residual), float4 epilogue
  gemm_bt<128, 128, 3, 4><<<2048, 256, 0, stream>>>(
      attn_o, wob, BD * HWD, CD, CD, bo, x, out, nullptr, nullptr, nullptr);
}